// Round 16
// baseline (561.691 us; speedup 1.0000x reference)
//
#include <hip/hip_runtime.h>
#include <math.h>

#define N_NODES 50000
#define E_EDGES 800000
#define E2 (E_EDGES + N_NODES)   // 850000 with self loops
#define M_PAD 50048              // 391 * 128
#define NBM 391                  // M_PAD / 128
#define GEMM_BLOCKS 1568         // 49 chunks * 32
#define FDIM 512
#define HID 256
#define HEADS 8
#define CDIM 32
#define LAYERS 3
#define GRAPHS 64
#define LN_EPS 1e-5f
#define POOL_P 16

typedef unsigned short ushort_t;
typedef __attribute__((ext_vector_type(8))) short short8v;
typedef __attribute__((ext_vector_type(4))) float f32x4;

__device__ __forceinline__ float bf2f(ushort_t u) {
    union { unsigned int i; float f; } v;
    v.i = ((unsigned int)u) << 16;
    return v.f;
}
__device__ __forceinline__ ushort_t f2bf(float f) {
    union { float f; unsigned int u; } v;
    v.f = f;
    unsigned int r = (v.u + 0x7FFFu + ((v.u >> 16) & 1u)) >> 16;
    return (ushort_t)r;
}
__device__ __forceinline__ void gload_lds16(const void* g, void* l) {
    __builtin_amdgcn_global_load_lds(
        (const __attribute__((address_space(1))) void*)g,
        (__attribute__((address_space(3))) void*)l, 16, 0, 0);
}

// ---------------------------------------------------------------- CSR scans
__global__ void k_scan1(const int* __restrict__ cnt, int* __restrict__ part) {
    __shared__ int s[256];
    int t = threadIdx.x;
    int i = blockIdx.x * 256 + t;
    s[t] = (i < N_NODES) ? cnt[i] : 0;
    __syncthreads();
    for (int d = 128; d > 0; d >>= 1) {
        if (t < d) s[t] += s[t + d];
        __syncthreads();
    }
    if (t == 0) part[blockIdx.x] = s[0];
}

__global__ void k_scan2(int* __restrict__ part, int nb, int* __restrict__ rowptr) {
    __shared__ int s[256];
    int t = threadIdx.x;
    int v = (t < nb) ? part[t] : 0;
    s[t] = v;
    __syncthreads();
    for (int d = 1; d < 256; d <<= 1) {
        int x = (t >= d) ? s[t - d] : 0;
        __syncthreads();
        s[t] += x;
        __syncthreads();
    }
    if (t < nb) part[t] = s[t] - v;
    if (t == 255) rowptr[N_NODES] = s[255];
}

__global__ void k_scan3(const int* __restrict__ cnt, const int* __restrict__ part,
                        int* __restrict__ rowptr) {
    __shared__ int s[256];
    int t = threadIdx.x;
    int i = blockIdx.x * 256 + t;
    int v = (i < N_NODES) ? cnt[i] : 0;
    s[t] = v;
    __syncthreads();
    for (int d = 1; d < 256; d <<= 1) {
        int x = (t >= d) ? s[t - d] : 0;
        __syncthreads();
        s[t] += x;
        __syncthreads();
    }
    if (i < N_NODES) rowptr[i] = part[blockIdx.x] + s[t] - v;
}

__global__ void k_fill(const int* __restrict__ ei, const int* __restrict__ rowptr,
                       int* __restrict__ fill, int* __restrict__ colv) {
    int e = blockIdx.x * 256 + threadIdx.x;
    if (e >= E2) return;
    int src, dst;
    if (e < E_EDGES) { src = ei[e]; dst = ei[E_EDGES + e]; }
    else             { src = dst = e - E_EDGES; }
    int pos = atomicAdd(&fill[dst], 1);
    colv[rowptr[dst] + pos] = src;
}

// ---------------------------------------------------------------- fused prep
// Cast segment (R15 post-mortem): the chunk-per-thread layout broke lane
// coalescing (64B-strided instructions). Correct form: each thread issues 4
// INDEPENDENT float4 loads at grid-span stride -- every instruction is
// lane-contiguous 16B/lane (1KB/wave), 64B/lane in flight.
//  [0, CAST_BLK)  : x fp32 -> xb bf16 (pad rows zeroed), 4x float4 / thread
//  [+GE_BLK)      : edge-count histogram, 4 edges / thread
//  [+NB_BLK)      : graph row bounds
//  [+WT_BLK)      : wt2 transposes (layers 1..2)
#define CAST_V4 ((int)((size_t)M_PAD * FDIM / 4))          // 6,406,144 float4 chunks
#define CAST_BLK (CAST_V4 / (4 * 256))                     // 6256
#define CAST_SPAN (CAST_BLK * 256)                         // threads in segment
#define GE_BLK ((E2 + 1023) / 1024)                        // 831 (4 edges/thread)
#define NB_BLK ((N_NODES + 255) / 256)                     // 196
#define MAT_ELEMS (HID * HID)
#define WT_TOTAL (2 * (LAYERS - 1) * MAT_ELEMS)
#define WT_BLK (WT_TOTAL / 256)                            // 1024
#define PREP2_BLOCKS (CAST_BLK + GE_BLK + NB_BLK + WT_BLK)

__global__ __launch_bounds__(256) void k_prep2(const float* __restrict__ x,
                                               const int* __restrict__ ei,
                                               const int* __restrict__ batch,
                                               const float* __restrict__ gat_w,
                                               const float* __restrict__ res_w,
                                               ushort_t* __restrict__ xb,
                                               int* __restrict__ cnt,
                                               int* __restrict__ rowstart,
                                               ushort_t* __restrict__ wt2) {
    int bid = blockIdx.x;
    if (bid < CAST_BLK) {
        const int gid = bid * 256 + threadIdx.x;
        // 4 independent, fully-coalesced streams
        int c4[4];
        float4 v[4];
        #pragma unroll
        for (int j = 0; j < 4; ++j) {
            c4[j] = gid + j * CAST_SPAN;                  // float4 index
            v[j] = ((const float4*)x)[c4[j]];
        }
        #pragma unroll
        for (int j = 0; j < 4; ++j) {
            int row = c4[j] >> 7;                         // 128 float4 per row
            ushort_t o[4];
            if (row < N_NODES) {
                o[0] = f2bf(v[j].x); o[1] = f2bf(v[j].y);
                o[2] = f2bf(v[j].z); o[3] = f2bf(v[j].w);
            } else {
                o[0] = o[1] = o[2] = o[3] = 0;
            }
            *(ushort4*)(xb + (size_t)c4[j] * 4) = *(ushort4*)o;
        }
        return;
    }
    bid -= CAST_BLK;
    if (bid < GE_BLK) {
        int e0 = bid * 1024 + threadIdx.x;
        #pragma unroll
        for (int j = 0; j < 4; ++j) {
            int e = e0 + j * 256;
            if (e < E2) {
                int dst = (e < E_EDGES) ? ei[E_EDGES + e] : (e - E_EDGES);
                atomicAdd(&cnt[dst], 1);
            }
        }
        return;
    }
    bid -= GE_BLK;
    if (bid < NB_BLK) {
        int n = bid * 256 + threadIdx.x;
        if (n >= N_NODES) return;
        int b = batch[n];
        int bp = (n == 0) ? -1 : batch[n - 1];
        for (int g = bp + 1; g <= b; ++g) rowstart[g] = n;
        if (n == N_NODES - 1) {
            for (int g = b + 1; g <= GRAPHS; ++g) rowstart[g] = N_NODES;
        }
        return;
    }
    bid -= NB_BLK;
    {
        int r = bid * 256 + threadIdx.x;
        int mat = r >> 16;            // 0..3
        int layer = 1 + (mat >> 1);
        int isgat = mat & 1;
        int within = r & 65535;
        int k = within >> 8, n = within & 255;
        const float* W = (isgat ? gat_w : res_w) + (size_t)layer * MAT_ELEMS;
        wt2[(size_t)layer * 512 * HID + (size_t)(isgat * 256 + n) * HID + k] =
            f2bf(W[within]);
    }
}

// Combined layer-0 weight + biases -- coalesced (R13-verified).
__global__ __launch_bounds__(256) void k_wcomb(const float* __restrict__ in_w,
                                               const float* __restrict__ in_b,
                                               const float* __restrict__ res_w0,
                                               const float* __restrict__ gat_w0,
                                               const float* __restrict__ res_b0,
                                               ushort_t* __restrict__ wtC,
                                               float* __restrict__ bC0,
                                               float* __restrict__ bC1) {
    __shared__ float irow[HID];
    const int f = blockIdx.x;
    const int n = threadIdx.x;
    irow[n] = (f == 512) ? in_b[n] : in_w[(size_t)f * HID + n];
    __syncthreads();
    float s0 = 0.f, s1 = 0.f;
    #pragma unroll 4
    for (int k = 0; k < HID; ++k) {
        float iv = irow[k];
        s0 += iv * bf2f(f2bf(res_w0[(size_t)k * HID + n]));
        s1 += iv * bf2f(f2bf(gat_w0[(size_t)k * HID + n]));
    }
    if (f == 512) {
        bC0[n] = s0 + res_b0[n];
        bC1[n] = s1;
    } else {
        wtC[(size_t)n * FDIM + f] = f2bf(s0);            // res half (rows 0..255)
        wtC[(size_t)(256 + n) * FDIM + f] = f2bf(s1);    // gat half (rows 256..511)
    }
}

// ---------------------------------------------------------------- bf16 MFMA GEMM
// 8-wave (512 thr), 128x128 tile, BK=32, 16KB LDS single buffer (R8/R10
// measured-best structure), compiler-scheduled barriers. 1D grid with XCD
// swizzle (R10-verified: A FETCH 103->30MB).
template<int K>
__global__ __launch_bounds__(512) void k_gemm_bf16(const ushort_t* __restrict__ A,
                                                   const ushort_t* __restrict__ BT,
                                                   const float* __restrict__ bias0,
                                                   const float* __restrict__ bias1,
                                                   ushort_t* __restrict__ C0,
                                                   ushort_t* __restrict__ C1,
                                                   const float* __restrict__ a_src,
                                                   const float* __restrict__ a_dst,
                                                   float* __restrict__ asn,
                                                   float* __restrict__ adn, int M) {
    const int L = blockIdx.x;
    const int chunk = L >> 5, wrd = L & 31;
    const int bmi = chunk * 8 + (wrd & 7);
    if (bmi >= NBM) return;
    const int bm = bmi * 128;
    const int bn = (wrd >> 3) * 128;

    __shared__ char lds[16384] __attribute__((aligned(16)));
    const int t = threadIdx.x, w = t >> 6, l = t & 63;
    const int wr = w & 3, wc = w >> 2;

    const int arow = t >> 2;
    const int aslot = (t & 3) ^ ((arow >> 1) & 3);
    const ushort_t* pa = A + (size_t)(bm + arow) * K + aslot * 8;
    const ushort_t* pb = BT + (size_t)(bn + arow) * K + aslot * 8;
    char* la = lds + w * 1024;
    char* lb = lds + 8192 + w * 1024;

    int aoff[2], boff[4];
    const int kb = l >> 4;
    #pragma unroll
    for (int mi = 0; mi < 2; ++mi) {
        int r = wr * 32 + mi * 16 + (l & 15);
        aoff[mi] = r * 64 + ((kb ^ ((r >> 1) & 3)) << 4);
    }
    #pragma unroll
    for (int ni = 0; ni < 4; ++ni) {
        int c = wc * 64 + ni * 16 + (l & 15);
        boff[ni] = 8192 + c * 64 + ((kb ^ ((c >> 1) & 3)) << 4);
    }

    f32x4 acc[2][4] = {};
    for (int k0 = 0; k0 < K; k0 += 32) {
        gload_lds16(pa + k0, la);
        gload_lds16(pb + k0, lb);
        __syncthreads();
        short8v a[2], b[4];
        #pragma unroll
        for (int mi = 0; mi < 2; ++mi) a[mi] = *(const short8v*)(lds + aoff[mi]);
        #pragma unroll
        for (int ni = 0; ni < 4; ++ni) b[ni] = *(const short8v*)(lds + boff[ni]);
        #pragma unroll
        for (int mi = 0; mi < 2; ++mi)
            #pragma unroll
            for (int ni = 0; ni < 4; ++ni)
                acc[mi][ni] = __builtin_amdgcn_mfma_f32_16x16x32_bf16(
                    a[mi], b[ni], acc[mi][ni], 0, 0, 0);
        __syncthreads();
    }

    ushort_t* C = (bn < 256) ? C0 : C1;
    const float* bias = (bn < 256) ? bias0 : bias1;
    const int cb = (bn < 256) ? bn : bn - 256;
    #pragma unroll
    for (int mi = 0; mi < 2; ++mi) {
        int row = bm + wr * 32 + mi * 16 + (l >> 4) * 4;
        #pragma unroll
        for (int ni = 0; ni < 4; ++ni) {
            int col = cb + wc * 64 + ni * 16 + (l & 15);
            float bv = bias ? bias[col] : 0.f;
            #pragma unroll
            for (int r = 0; r < 4; ++r) {
                if (row + r < M)
                    C[(size_t)(row + r) * HID + col] = f2bf(acc[mi][ni][r] + bv);
            }
        }
    }

    if (asn && bn >= 256) {
        const int cbase = bn - 256;                    // 0 or 128
        #pragma unroll
        for (int mi = 0; mi < 2; ++mi) {
            int row = bm + wr * 32 + mi * 16 + (l >> 4) * 4;
            #pragma unroll
            for (int p = 0; p < 2; ++p) {
                int c0 = cbase + wc * 64 + (2 * p) * 16 + (l & 15);
                int c1c = c0 + 16;
                int head = c0 >> 5;
                float b1a = bias1 ? bias1[c0] : 0.f;
                float b1b = bias1 ? bias1[c1c] : 0.f;
                float as0 = a_src[c0], as1 = a_src[c1c];
                float ad0 = a_dst[c0], ad1 = a_dst[c1c];
                float vs[4], vd[4];
                #pragma unroll
                for (int r = 0; r < 4; ++r) {
                    float x0 = acc[mi][2 * p][r] + b1a;
                    float x1 = acc[mi][2 * p + 1][r] + b1b;
                    vs[r] = x0 * as0 + x1 * as1;
                    vd[r] = x0 * ad0 + x1 * ad1;
                }
                #pragma unroll
                for (int d = 1; d < 16; d <<= 1) {
                    #pragma unroll
                    for (int r = 0; r < 4; ++r) {
                        vs[r] += __shfl_xor(vs[r], d);
                        vd[r] += __shfl_xor(vd[r], d);
                    }
                }
                if ((l & 15) == 0) {
                    #pragma unroll
                    for (int r = 0; r < 4; ++r) {
                        if (row + r < N_NODES) {
                            asn[(row + r) * HEADS + head] = vs[r];
                            adn[(row + r) * HEADS + head] = vd[r];
                        }
                    }
                }
            }
        }
    }
}

// ---------------------------------------------------------------- aggregation + residual + LN + ReLU
__global__ __launch_bounds__(256) void k_agg_ln(const ushort_t* __restrict__ xhb,
                                                const float* __restrict__ asn,
                                                const float* __restrict__ adn,
                                                const int* __restrict__ rowptr,
                                                const int* __restrict__ colv,
                                                const ushort_t* __restrict__ hresb,
                                                const float* __restrict__ gb,
                                                const float* __restrict__ g,
                                                const float* __restrict__ b,
                                                ushort_t* __restrict__ hb) {
    const int wave = threadIdx.x >> 6, lane = threadIdx.x & 63;
    const int n = blockIdx.x * 4 + wave;
    if (n >= N_NODES) return;
    const int half = lane >> 5;
    const int lh = lane & 31;
    const int head = lh >> 2;
    const int ch0 = lh * 8;
    const float adn_h = adn[n * HEADS + head];
    const int j0 = rowptr[n], j1 = rowptr[n + 1];

    float acc[8] = {};
    float den = 0.f;
    int base = j0;
    for (; base + 8 <= j1; base += 8) {
        int idx[4];
        #pragma unroll
        for (int q = 0; q < 4; ++q) idx[q] = colv[base + 2 * q + half];
        short8v u[4];
        #pragma unroll
        for (int q = 0; q < 4; ++q)
            u[q] = *(const short8v*)(xhb + (size_t)idx[q] * HID + ch0);
        float p[4];
        #pragma unroll
        for (int q = 0; q < 4; ++q) {
            float e = asn[idx[q] * HEADS + head] + adn_h;
            e = (e > 0.f) ? e : 0.2f * e;
            p[q] = __expf(e);
        }
        #pragma unroll
        for (int q = 0; q < 4; ++q) {
            den += p[q];
            #pragma unroll
            for (int c = 0; c < 8; ++c)
                acc[c] += p[q] * bf2f((ushort_t)u[q][c]);
        }
    }
    for (; base < j1; base += 2) {
        bool valid = (base + half) < j1;
        int s = valid ? colv[base + half] : n;
        short8v u = *(const short8v*)(xhb + (size_t)s * HID + ch0);
        float e = asn[s * HEADS + head] + adn_h;
        e = (e > 0.f) ? e : 0.2f * e;
        float p = valid ? __expf(e) : 0.f;
        den += p;
        #pragma unroll
        for (int c = 0; c < 8; ++c)
            acc[c] += p * bf2f((ushort_t)u[c]);
    }
    den += __shfl_xor(den, 32);
    #pragma unroll
    for (int c = 0; c < 8; ++c) acc[c] += __shfl_xor(acc[c], 32);

    const float inv = 1.f / (den + 1e-16f);
    short8v hr = *(const short8v*)(hresb + (size_t)n * HID + ch0);
    float4 gbA = *(const float4*)(gb + ch0);
    float4 gbB = *(const float4*)(gb + ch0 + 4);
    float v[8];
    #pragma unroll
    for (int c = 0; c < 8; ++c) {
        float gbv = (c < 4) ? ((const float*)&gbA)[c] : ((const float*)&gbB)[c - 4];
        v[c] = acc[c] * inv + bf2f((ushort_t)hr[c]) + gbv;
    }
    float s = 0.f;
    #pragma unroll
    for (int c = 0; c < 8; ++c) s += v[c];
    #pragma unroll
    for (int d = 1; d < 32; d <<= 1) s += __shfl_xor(s, d);
    const float mu = s * (1.f / HID);
    float q = 0.f;
    #pragma unroll
    for (int c = 0; c < 8; ++c) {
        v[c] -= mu;
        q += v[c] * v[c];
    }
    #pragma unroll
    for (int d = 1; d < 32; d <<= 1) q += __shfl_xor(q, d);
    const float rstd = rsqrtf(q * (1.f / HID) + LN_EPS);
    float4 gA = *(const float4*)(g + ch0);
    float4 gB = *(const float4*)(g + ch0 + 4);
    float4 bA = *(const float4*)(b + ch0);
    float4 bB = *(const float4*)(b + ch0 + 4);
    ushort_t o[8];
    #pragma unroll
    for (int c = 0; c < 8; ++c) {
        float gv = (c < 4) ? ((const float*)&gA)[c] : ((const float*)&gB)[c - 4];
        float bv = (c < 4) ? ((const float*)&bA)[c] : ((const float*)&bB)[c - 4];
        o[c] = f2bf(fmaxf(v[c] * rstd * gv + bv, 0.f));
    }
    if (half == 0)
        *(short8v*)(hb + (size_t)n * HID + ch0) = *(short8v*)o;
}

// ---------------------------------------------------------------- pooling
__global__ __launch_bounds__(256) void k_pool1(const ushort_t* __restrict__ hb,
                                               const int* __restrict__ rowstart,
                                               float* __restrict__ part) {
    int g = blockIdx.x, p = blockIdx.y, c = threadIdx.x;
    int s0 = rowstart[g], s1 = rowstart[g + 1];
    float sum = 0.f, mx = -INFINITY;
    for (int n = s0 + p; n < s1; n += POOL_P) {
        float v = bf2f(hb[(size_t)n * HID + c]);
        sum += v;
        mx = fmaxf(mx, v);
    }
    float* pp = part + (size_t)(g * POOL_P + p) * 512;
    pp[c] = sum;
    pp[256 + c] = mx;
}

__global__ __launch_bounds__(256) void k_pool2g(const float* __restrict__ part,
                                                const int* __restrict__ rowstart,
                                                const float* __restrict__ W,
                                                const float* __restrict__ bias,
                                                float* __restrict__ out) {
    __shared__ float hc[512];
    int g = blockIdx.x, c = threadIdx.x;
    float sum = 0.f, mx = -INFINITY;
    for (int p = 0; p < POOL_P; ++p) {
        const float* pp = part + (size_t)(g * POOL_P + p) * 512;
        sum += pp[c];
        mx = fmaxf(mx, pp[256 + c]);
    }
    float cntf = (float)(rowstart[g + 1] - rowstart[g]);
    hc[c] = sum / fmaxf(cntf, 1.f);
    hc[256 + c] = mx;
    __syncthreads();
    float acc = bias[c];
    #pragma unroll 8
    for (int k = 0; k < 2 * HID; ++k)
        acc += hc[k] * W[(size_t)k * HID + c];
    out[(size_t)g * HID + c] = fmaxf(acc, 0.f);
}

// ---------------------------------------------------------------- launch
extern "C" void kernel_launch(void* const* d_in, const int* in_sizes, int n_in,
                              void* d_out, int out_size, void* d_ws, size_t ws_size,
                              hipStream_t stream) {
    const float* x       = (const float*)d_in[0];
    const int*   ei      = (const int*)d_in[1];
    const int*   batch   = (const int*)d_in[2];
    const float* in_w    = (const float*)d_in[3];
    const float* in_b    = (const float*)d_in[4];
    const float* gat_w   = (const float*)d_in[5];
    const float* att_src = (const float*)d_in[6];
    const float* att_dst = (const float*)d_in[7];
    const float* gat_b   = (const float*)d_in[8];
    const float* res_w   = (const float*)d_in[9];
    const float* res_b   = (const float*)d_in[10];
    const float* ln_g    = (const float*)d_in[11];
    const float* ln_b    = (const float*)d_in[12];
    const float* pool_w  = (const float*)d_in[13];
    const float* pool_b  = (const float*)d_in[14];
    float* out = (float*)d_out;

    char* ws = (char*)d_ws;
    size_t off = 0;
    auto alloc = [&](size_t bytes) -> char* {
        char* p = ws + off;
        off = (off + bytes + 255) & ~(size_t)255;
        return p;
    };
    ushort_t* xb    = (ushort_t*)alloc((size_t)M_PAD * FDIM * 2);
    ushort_t* hb    = (ushort_t*)alloc((size_t)M_PAD * HID * 2);
    ushort_t* xhb   = (ushort_t*)alloc((size_t)M_PAD * HID * 2);
    ushort_t* hresb = (ushort_t*)alloc((size_t)M_PAD * HID * 2);
    float* asn      = (float*)alloc((size_t)N_NODES * HEADS * 4);
    float* adn      = (float*)alloc((size_t)N_NODES * HEADS * 4);
    int*   cnt      = (int*)alloc((size_t)N_NODES * 4);
    int*   fill     = (int*)alloc((size_t)N_NODES * 4);
    int*   rowptr   = (int*)alloc((size_t)(N_NODES + 1) * 4);
    int*   colv     = (int*)alloc((size_t)E2 * 4);
    int*   part     = (int*)alloc(256 * 4);
    int*   rowstart = (int*)alloc((size_t)(GRAPHS + 1) * 4);
    ushort_t* wt2   = (ushort_t*)alloc((size_t)LAYERS * 512 * HID * 2);
    ushort_t* wtC   = (ushort_t*)alloc((size_t)512 * FDIM * 2);
    float* bC0      = (float*)alloc(HID * 4);
    float* bC1      = (float*)alloc(HID * 4);
    float* poolpart = (float*)alloc((size_t)GRAPHS * POOL_P * 512 * 4);

    hipMemsetAsync(cnt, 0, (size_t)N_NODES * 4, stream);
    hipMemsetAsync(fill, 0, (size_t)N_NODES * 4, stream);

    const int ge = (E2 + 255) / 256;
    const int nb = (N_NODES + 255) / 256;

    // fused prep: cast_x (coalesced deep-flight) + count + bounds + wtrans
    k_prep2<<<PREP2_BLOCKS, 256, 0, stream>>>(x, ei, batch, gat_w, res_w,
                                              xb, cnt, rowstart, wt2);
    k_wcomb<<<513, 256, 0, stream>>>(in_w, in_b, res_w, gat_w, res_b,
                                     wtC, bC0, bC1);
    k_scan1<<<nb, 256, 0, stream>>>(cnt, part);
    k_scan2<<<1, 256, 0, stream>>>(part, nb, rowptr);
    k_scan3<<<nb, 256, 0, stream>>>(cnt, part, rowptr);
    k_fill<<<ge, 256, 0, stream>>>(ei, rowptr, fill, colv);

    const int nw = (N_NODES + 3) / 4;

    // ---- layer 0 (input projection folded): A = xb, K = 512 ----
    k_gemm_bf16<FDIM><<<GEMM_BLOCKS, 512, 0, stream>>>(xb, wtC, bC0, bC1,
                                                       hresb, xhb, att_src, att_dst,
                                                       asn, adn, N_NODES);
    k_agg_ln<<<nw, 256, 0, stream>>>(xhb, asn, adn, rowptr, colv, hresb,
                                     gat_b, ln_g, ln_b, hb);

    // ---- layers 1..2: A = hb, K = 256 ----
    for (int i = 1; i < LAYERS; ++i) {
        k_gemm_bf16<HID><<<GEMM_BLOCKS, 512, 0, stream>>>(
            hb, wt2 + (size_t)i * 512 * HID,
            res_b + (size_t)i * HID, nullptr, hresb, xhb,
            att_src + (size_t)i * HEADS * CDIM,
            att_dst + (size_t)i * HEADS * CDIM, asn, adn, N_NODES);
        k_agg_ln<<<nw, 256, 0, stream>>>(xhb, asn, adn, rowptr, colv, hresb,
                                         gat_b + (size_t)i * HID,
                                         ln_g + (size_t)i * HID,
                                         ln_b + (size_t)i * HID, hb);
    }
    dim3 pg(GRAPHS, POOL_P);
    k_pool1<<<pg, 256, 0, stream>>>(hb, rowstart, poolpart);
    k_pool2g<<<GRAPHS, 256, 0, stream>>>(poolpart, rowstart, pool_w, pool_b, out);
}

// Round 17
// 541.864 us; speedup vs baseline: 1.0366x; 1.0366x over previous
//
#include <hip/hip_runtime.h>
#include <math.h>

#define N_NODES 50000
#define E_EDGES 800000
#define E2 (E_EDGES + N_NODES)   // 850000 with self loops
#define M_PAD 50048              // 391 * 128
#define NBM 391                  // M_PAD / 128
#define GEMM_BLOCKS 1568         // 49 chunks * 32
#define FILL_BLK ((E2 + 1023) / 1024)   // 831 (512 thr x 2 edges)
#define FDIM 512
#define HID 256
#define HEADS 8
#define CDIM 32
#define LAYERS 3
#define GRAPHS 64
#define LN_EPS 1e-5f
#define POOL_P 16

typedef unsigned short ushort_t;
typedef __attribute__((ext_vector_type(8))) short short8v;
typedef __attribute__((ext_vector_type(4))) float f32x4;

__device__ __forceinline__ float bf2f(ushort_t u) {
    union { unsigned int i; float f; } v;
    v.i = ((unsigned int)u) << 16;
    return v.f;
}
__device__ __forceinline__ ushort_t f2bf(float f) {
    union { float f; unsigned int u; } v;
    v.f = f;
    unsigned int r = (v.u + 0x7FFFu + ((v.u >> 16) & 1u)) >> 16;
    return (ushort_t)r;
}
__device__ __forceinline__ void gload_lds16(const void* g, void* l) {
    __builtin_amdgcn_global_load_lds(
        (const __attribute__((address_space(1))) void*)g,
        (__attribute__((address_space(3))) void*)l, 16, 0, 0);
}

// ---------------------------------------------------------------- CSR scans
__global__ void k_scan1(const int* __restrict__ cnt, int* __restrict__ part) {
    __shared__ int s[256];
    int t = threadIdx.x;
    int i = blockIdx.x * 256 + t;
    s[t] = (i < N_NODES) ? cnt[i] : 0;
    __syncthreads();
    for (int d = 128; d > 0; d >>= 1) {
        if (t < d) s[t] += s[t + d];
        __syncthreads();
    }
    if (t == 0) part[blockIdx.x] = s[0];
}

__global__ void k_scan2(int* __restrict__ part, int nb, int* __restrict__ rowptr) {
    __shared__ int s[256];
    int t = threadIdx.x;
    int v = (t < nb) ? part[t] : 0;
    s[t] = v;
    __syncthreads();
    for (int d = 1; d < 256; d <<= 1) {
        int x = (t >= d) ? s[t - d] : 0;
        __syncthreads();
        s[t] += x;
        __syncthreads();
    }
    if (t < nb) part[t] = s[t] - v;
    if (t == 255) rowptr[N_NODES] = s[255];
}

__global__ void k_scan3(const int* __restrict__ cnt, const int* __restrict__ part,
                        int* __restrict__ rowptr) {
    __shared__ int s[256];
    int t = threadIdx.x;
    int i = blockIdx.x * 256 + t;
    int v = (i < N_NODES) ? cnt[i] : 0;
    s[t] = v;
    __syncthreads();
    for (int d = 1; d < 256; d <<= 1) {
        int x = (t >= d) ? s[t - d] : 0;
        __syncthreads();
        s[t] += x;
        __syncthreads();
    }
    if (i < N_NODES) rowptr[i] = part[blockIdx.x] + s[t] - v;
}

// ---------------------------------------------------------------- fused prep
// R14-form (measured-equal to all cast variants; atomic segment co-limits):
//  [0, CAST_BLK)  : x fp32 -> xb bf16 (pad rows zeroed), 8 elems/thread
//  [+GE_BLK)      : edge-count histogram (CSR step 1)
//  [+NB_BLK)      : graph row bounds
//  [+WT_BLK)      : wt2 transposes (layers 1..2)
#define CAST_BLK ((int)((size_t)M_PAD * FDIM / 8 / 256))   // 12512
#define GE_BLK ((E2 + 255) / 256)                          // 3321
#define NB_BLK ((N_NODES + 255) / 256)                     // 196
#define MAT_ELEMS (HID * HID)
#define WT_TOTAL (2 * (LAYERS - 1) * MAT_ELEMS)
#define WT_BLK (WT_TOTAL / 256)                            // 1024
#define PREP2_BLOCKS (CAST_BLK + GE_BLK + NB_BLK + WT_BLK)

__global__ __launch_bounds__(256) void k_prep2(const float* __restrict__ x,
                                               const int* __restrict__ ei,
                                               const int* __restrict__ batch,
                                               const float* __restrict__ gat_w,
                                               const float* __restrict__ res_w,
                                               ushort_t* __restrict__ xb,
                                               int* __restrict__ cnt,
                                               int* __restrict__ rowstart,
                                               ushort_t* __restrict__ wt2) {
    int bid = blockIdx.x;
    if (bid < CAST_BLK) {
        long long i8 = ((long long)bid * 256 + threadIdx.x) * 8;
        int row = (int)(i8 >> 9);
        ushort_t o[8];
        if (row < N_NODES) {
            const float* p = x + i8;
            #pragma unroll
            for (int j = 0; j < 8; ++j) o[j] = f2bf(p[j]);
        } else {
            #pragma unroll
            for (int j = 0; j < 8; ++j) o[j] = 0;
        }
        *(short8v*)(xb + i8) = *(short8v*)o;
        return;
    }
    bid -= CAST_BLK;
    if (bid < GE_BLK) {
        int e = bid * 256 + threadIdx.x;
        if (e >= E2) return;
        int dst = (e < E_EDGES) ? ei[E_EDGES + e] : (e - E_EDGES);
        atomicAdd(&cnt[dst], 1);
        return;
    }
    bid -= GE_BLK;
    if (bid < NB_BLK) {
        int n = bid * 256 + threadIdx.x;
        if (n >= N_NODES) return;
        int b = batch[n];
        int bp = (n == 0) ? -1 : batch[n - 1];
        for (int g = bp + 1; g <= b; ++g) rowstart[g] = n;
        if (n == N_NODES - 1) {
            for (int g = b + 1; g <= GRAPHS; ++g) rowstart[g] = N_NODES;
        }
        return;
    }
    bid -= NB_BLK;
    {
        int r = bid * 256 + threadIdx.x;
        int mat = r >> 16;            // 0..3
        int layer = 1 + (mat >> 1);
        int isgat = mat & 1;
        int within = r & 65535;
        int k = within >> 8, n = within & 255;
        const float* W = (isgat ? gat_w : res_w) + (size_t)layer * MAT_ELEMS;
        wt2[(size_t)layer * 512 * HID + (size_t)(isgat * 256 + n) * HID + k] =
            f2bf(W[within]);
    }
}

// Combined layer-0 weight + biases -- coalesced (R13-verified).
__global__ __launch_bounds__(256) void k_wcomb(const float* __restrict__ in_w,
                                               const float* __restrict__ in_b,
                                               const float* __restrict__ res_w0,
                                               const float* __restrict__ gat_w0,
                                               const float* __restrict__ res_b0,
                                               ushort_t* __restrict__ wtC,
                                               float* __restrict__ bC0,
                                               float* __restrict__ bC1) {
    __shared__ float irow[HID];
    const int f = blockIdx.x;
    const int n = threadIdx.x;
    irow[n] = (f == 512) ? in_b[n] : in_w[(size_t)f * HID + n];
    __syncthreads();
    float s0 = 0.f, s1 = 0.f;
    #pragma unroll 4
    for (int k = 0; k < HID; ++k) {
        float iv = irow[k];
        s0 += iv * bf2f(f2bf(res_w0[(size_t)k * HID + n]));
        s1 += iv * bf2f(f2bf(gat_w0[(size_t)k * HID + n]));
    }
    if (f == 512) {
        bC0[n] = s0 + res_b0[n];
        bC1[n] = s1;
    } else {
        wtC[(size_t)n * FDIM + f] = f2bf(s0);            // res half (rows 0..255)
        wtC[(size_t)(256 + n) * FDIM + f] = f2bf(s1);    // gat half (rows 256..511)
    }
}

// ---------------------------------------------------------------- bf16 MFMA GEMM (+ fused CSR fill)
// 8-wave (512 thr), 128x128 tile, BK=32, 16KB LDS single buffer (R8/R10
// measured-best), compiler-scheduled barriers, 1D grid with XCD swizzle
// (R10-verified). Blocks >= GEMM_BLOCKS run the CSR fill segment (850K
// device-scope atomics + random scatter) -- hidden under the latency-bound
// GEMM (R16 post-mortem: atomics resolve at the device-coherent point and
// were serializing as a standalone dispatch).
template<int K>
__global__ __launch_bounds__(512) void k_gemm_bf16(const ushort_t* __restrict__ A,
                                                   const ushort_t* __restrict__ BT,
                                                   const float* __restrict__ bias0,
                                                   const float* __restrict__ bias1,
                                                   ushort_t* __restrict__ C0,
                                                   ushort_t* __restrict__ C1,
                                                   const float* __restrict__ a_src,
                                                   const float* __restrict__ a_dst,
                                                   float* __restrict__ asn,
                                                   float* __restrict__ adn, int M,
                                                   const int* __restrict__ ei,
                                                   const int* __restrict__ rowptr,
                                                   int* __restrict__ fillc,
                                                   int* __restrict__ colv) {
    const int L = blockIdx.x;
    if (L >= GEMM_BLOCKS) {
        // ---- CSR fill segment ----
        int e0 = (L - GEMM_BLOCKS) * 1024 + threadIdx.x;
        #pragma unroll
        for (int j = 0; j < 2; ++j) {
            int e = e0 + j * 512;
            if (e < E2) {
                int src, dst;
                if (e < E_EDGES) { src = ei[e]; dst = ei[E_EDGES + e]; }
                else             { src = dst = e - E_EDGES; }
                int pos = atomicAdd(&fillc[dst], 1);
                colv[rowptr[dst] + pos] = src;
            }
        }
        return;
    }
    const int chunk = L >> 5, wrd = L & 31;
    const int bmi = chunk * 8 + (wrd & 7);
    if (bmi >= NBM) return;
    const int bm = bmi * 128;
    const int bn = (wrd >> 3) * 128;

    __shared__ char lds[16384] __attribute__((aligned(16)));
    const int t = threadIdx.x, w = t >> 6, l = t & 63;
    const int wr = w & 3, wc = w >> 2;

    const int arow = t >> 2;
    const int aslot = (t & 3) ^ ((arow >> 1) & 3);
    const ushort_t* pa = A + (size_t)(bm + arow) * K + aslot * 8;
    const ushort_t* pb = BT + (size_t)(bn + arow) * K + aslot * 8;
    char* la = lds + w * 1024;
    char* lb = lds + 8192 + w * 1024;

    int aoff[2], boff[4];
    const int kb = l >> 4;
    #pragma unroll
    for (int mi = 0; mi < 2; ++mi) {
        int r = wr * 32 + mi * 16 + (l & 15);
        aoff[mi] = r * 64 + ((kb ^ ((r >> 1) & 3)) << 4);
    }
    #pragma unroll
    for (int ni = 0; ni < 4; ++ni) {
        int c = wc * 64 + ni * 16 + (l & 15);
        boff[ni] = 8192 + c * 64 + ((kb ^ ((c >> 1) & 3)) << 4);
    }

    f32x4 acc[2][4] = {};
    for (int k0 = 0; k0 < K; k0 += 32) {
        gload_lds16(pa + k0, la);
        gload_lds16(pb + k0, lb);
        __syncthreads();
        short8v a[2], b[4];
        #pragma unroll
        for (int mi = 0; mi < 2; ++mi) a[mi] = *(const short8v*)(lds + aoff[mi]);
        #pragma unroll
        for (int ni = 0; ni < 4; ++ni) b[ni] = *(const short8v*)(lds + boff[ni]);
        #pragma unroll
        for (int mi = 0; mi < 2; ++mi)
            #pragma unroll
            for (int ni = 0; ni < 4; ++ni)
                acc[mi][ni] = __builtin_amdgcn_mfma_f32_16x16x32_bf16(
                    a[mi], b[ni], acc[mi][ni], 0, 0, 0);
        __syncthreads();
    }

    ushort_t* C = (bn < 256) ? C0 : C1;
    const float* bias = (bn < 256) ? bias0 : bias1;
    const int cb = (bn < 256) ? bn : bn - 256;
    #pragma unroll
    for (int mi = 0; mi < 2; ++mi) {
        int row = bm + wr * 32 + mi * 16 + (l >> 4) * 4;
        #pragma unroll
        for (int ni = 0; ni < 4; ++ni) {
            int col = cb + wc * 64 + ni * 16 + (l & 15);
            float bv = bias ? bias[col] : 0.f;
            #pragma unroll
            for (int r = 0; r < 4; ++r) {
                if (row + r < M)
                    C[(size_t)(row + r) * HID + col] = f2bf(acc[mi][ni][r] + bv);
            }
        }
    }

    if (asn && bn >= 256) {
        const int cbase = bn - 256;                    // 0 or 128
        #pragma unroll
        for (int mi = 0; mi < 2; ++mi) {
            int row = bm + wr * 32 + mi * 16 + (l >> 4) * 4;
            #pragma unroll
            for (int p = 0; p < 2; ++p) {
                int c0 = cbase + wc * 64 + (2 * p) * 16 + (l & 15);
                int c1c = c0 + 16;
                int head = c0 >> 5;
                float b1a = bias1 ? bias1[c0] : 0.f;
                float b1b = bias1 ? bias1[c1c] : 0.f;
                float as0 = a_src[c0], as1 = a_src[c1c];
                float ad0 = a_dst[c0], ad1 = a_dst[c1c];
                float vs[4], vd[4];
                #pragma unroll
                for (int r = 0; r < 4; ++r) {
                    float x0 = acc[mi][2 * p][r] + b1a;
                    float x1 = acc[mi][2 * p + 1][r] + b1b;
                    vs[r] = x0 * as0 + x1 * as1;
                    vd[r] = x0 * ad0 + x1 * ad1;
                }
                #pragma unroll
                for (int d = 1; d < 16; d <<= 1) {
                    #pragma unroll
                    for (int r = 0; r < 4; ++r) {
                        vs[r] += __shfl_xor(vs[r], d);
                        vd[r] += __shfl_xor(vd[r], d);
                    }
                }
                if ((l & 15) == 0) {
                    #pragma unroll
                    for (int r = 0; r < 4; ++r) {
                        if (row + r < N_NODES) {
                            asn[(row + r) * HEADS + head] = vs[r];
                            adn[(row + r) * HEADS + head] = vd[r];
                        }
                    }
                }
            }
        }
    }
}

// ---------------------------------------------------------------- aggregation + residual + LN + ReLU
__global__ __launch_bounds__(256) void k_agg_ln(const ushort_t* __restrict__ xhb,
                                                const float* __restrict__ asn,
                                                const float* __restrict__ adn,
                                                const int* __restrict__ rowptr,
                                                const int* __restrict__ colv,
                                                const ushort_t* __restrict__ hresb,
                                                const float* __restrict__ gb,
                                                const float* __restrict__ g,
                                                const float* __restrict__ b,
                                                ushort_t* __restrict__ hb) {
    const int wave = threadIdx.x >> 6, lane = threadIdx.x & 63;
    const int n = blockIdx.x * 4 + wave;
    if (n >= N_NODES) return;
    const int half = lane >> 5;
    const int lh = lane & 31;
    const int head = lh >> 2;
    const int ch0 = lh * 8;
    const float adn_h = adn[n * HEADS + head];
    const int j0 = rowptr[n], j1 = rowptr[n + 1];

    float acc[8] = {};
    float den = 0.f;
    int base = j0;
    for (; base + 8 <= j1; base += 8) {
        int idx[4];
        #pragma unroll
        for (int q = 0; q < 4; ++q) idx[q] = colv[base + 2 * q + half];
        short8v u[4];
        #pragma unroll
        for (int q = 0; q < 4; ++q)
            u[q] = *(const short8v*)(xhb + (size_t)idx[q] * HID + ch0);
        float p[4];
        #pragma unroll
        for (int q = 0; q < 4; ++q) {
            float e = asn[idx[q] * HEADS + head] + adn_h;
            e = (e > 0.f) ? e : 0.2f * e;
            p[q] = __expf(e);
        }
        #pragma unroll
        for (int q = 0; q < 4; ++q) {
            den += p[q];
            #pragma unroll
            for (int c = 0; c < 8; ++c)
                acc[c] += p[q] * bf2f((ushort_t)u[q][c]);
        }
    }
    for (; base < j1; base += 2) {
        bool valid = (base + half) < j1;
        int s = valid ? colv[base + half] : n;
        short8v u = *(const short8v*)(xhb + (size_t)s * HID + ch0);
        float e = asn[s * HEADS + head] + adn_h;
        e = (e > 0.f) ? e : 0.2f * e;
        float p = valid ? __expf(e) : 0.f;
        den += p;
        #pragma unroll
        for (int c = 0; c < 8; ++c)
            acc[c] += p * bf2f((ushort_t)u[c]);
    }
    den += __shfl_xor(den, 32);
    #pragma unroll
    for (int c = 0; c < 8; ++c) acc[c] += __shfl_xor(acc[c], 32);

    const float inv = 1.f / (den + 1e-16f);
    short8v hr = *(const short8v*)(hresb + (size_t)n * HID + ch0);
    float4 gbA = *(const float4*)(gb + ch0);
    float4 gbB = *(const float4*)(gb + ch0 + 4);
    float v[8];
    #pragma unroll
    for (int c = 0; c < 8; ++c) {
        float gbv = (c < 4) ? ((const float*)&gbA)[c] : ((const float*)&gbB)[c - 4];
        v[c] = acc[c] * inv + bf2f((ushort_t)hr[c]) + gbv;
    }
    float s = 0.f;
    #pragma unroll
    for (int c = 0; c < 8; ++c) s += v[c];
    #pragma unroll
    for (int d = 1; d < 32; d <<= 1) s += __shfl_xor(s, d);
    const float mu = s * (1.f / HID);
    float q = 0.f;
    #pragma unroll
    for (int c = 0; c < 8; ++c) {
        v[c] -= mu;
        q += v[c] * v[c];
    }
    #pragma unroll
    for (int d = 1; d < 32; d <<= 1) q += __shfl_xor(q, d);
    const float rstd = rsqrtf(q * (1.f / HID) + LN_EPS);
    float4 gA = *(const float4*)(g + ch0);
    float4 gB = *(const float4*)(g + ch0 + 4);
    float4 bA = *(const float4*)(b + ch0);
    float4 bB = *(const float4*)(b + ch0 + 4);
    ushort_t o[8];
    #pragma unroll
    for (int c = 0; c < 8; ++c) {
        float gv = (c < 4) ? ((const float*)&gA)[c] : ((const float*)&gB)[c - 4];
        float bv = (c < 4) ? ((const float*)&bA)[c] : ((const float*)&bB)[c - 4];
        o[c] = f2bf(fmaxf(v[c] * rstd * gv + bv, 0.f));
    }
    if (half == 0)
        *(short8v*)(hb + (size_t)n * HID + ch0) = *(short8v*)o;
}

// ---------------------------------------------------------------- pooling
__global__ __launch_bounds__(256) void k_pool1(const ushort_t* __restrict__ hb,
                                               const int* __restrict__ rowstart,
                                               float* __restrict__ part) {
    int g = blockIdx.x, p = blockIdx.y, c = threadIdx.x;
    int s0 = rowstart[g], s1 = rowstart[g + 1];
    float sum = 0.f, mx = -INFINITY;
    for (int n = s0 + p; n < s1; n += POOL_P) {
        float v = bf2f(hb[(size_t)n * HID + c]);
        sum += v;
        mx = fmaxf(mx, v);
    }
    float* pp = part + (size_t)(g * POOL_P + p) * 512;
    pp[c] = sum;
    pp[256 + c] = mx;
}

__global__ __launch_bounds__(256) void k_pool2g(const float* __restrict__ part,
                                                const int* __restrict__ rowstart,
                                                const float* __restrict__ W,
                                                const float* __restrict__ bias,
                                                float* __restrict__ out) {
    __shared__ float hc[512];
    int g = blockIdx.x, c = threadIdx.x;
    float sum = 0.f, mx = -INFINITY;
    for (int p = 0; p < POOL_P; ++p) {
        const float* pp = part + (size_t)(g * POOL_P + p) * 512;
        sum += pp[c];
        mx = fmaxf(mx, pp[256 + c]);
    }
    float cntf = (float)(rowstart[g + 1] - rowstart[g]);
    hc[c] = sum / fmaxf(cntf, 1.f);
    hc[256 + c] = mx;
    __syncthreads();
    float acc = bias[c];
    #pragma unroll 8
    for (int k = 0; k < 2 * HID; ++k)
        acc += hc[k] * W[(size_t)k * HID + c];
    out[(size_t)g * HID + c] = fmaxf(acc, 0.f);
}

// ---------------------------------------------------------------- launch
extern "C" void kernel_launch(void* const* d_in, const int* in_sizes, int n_in,
                              void* d_out, int out_size, void* d_ws, size_t ws_size,
                              hipStream_t stream) {
    const float* x       = (const float*)d_in[0];
    const int*   ei      = (const int*)d_in[1];
    const int*   batch   = (const int*)d_in[2];
    const float* in_w    = (const float*)d_in[3];
    const float* in_b    = (const float*)d_in[4];
    const float* gat_w   = (const float*)d_in[5];
    const float* att_src = (const float*)d_in[6];
    const float* att_dst = (const float*)d_in[7];
    const float* gat_b   = (const float*)d_in[8];
    const float* res_w   = (const float*)d_in[9];
    const float* res_b   = (const float*)d_in[10];
    const float* ln_g    = (const float*)d_in[11];
    const float* ln_b    = (const float*)d_in[12];
    const float* pool_w  = (const float*)d_in[13];
    const float* pool_b  = (const float*)d_in[14];
    float* out = (float*)d_out;

    char* ws = (char*)d_ws;
    size_t off = 0;
    auto alloc = [&](size_t bytes) -> char* {
        char* p = ws + off;
        off = (off + bytes + 255) & ~(size_t)255;
        return p;
    };
    ushort_t* xb    = (ushort_t*)alloc((size_t)M_PAD * FDIM * 2);
    ushort_t* hb    = (ushort_t*)alloc((size_t)M_PAD * HID * 2);
    ushort_t* xhb   = (ushort_t*)alloc((size_t)M_PAD * HID * 2);
    ushort_t* hresb = (ushort_t*)alloc((size_t)M_PAD * HID * 2);
    float* asn      = (float*)alloc((size_t)N_NODES * HEADS * 4);
    float* adn      = (float*)alloc((size_t)N_NODES * HEADS * 4);
    int*   cnt      = (int*)alloc((size_t)N_NODES * 4);
    int*   fill     = (int*)alloc((size_t)N_NODES * 4);
    int*   rowptr   = (int*)alloc((size_t)(N_NODES + 1) * 4);
    int*   colv     = (int*)alloc((size_t)E2 * 4);
    int*   part     = (int*)alloc(256 * 4);
    int*   rowstart = (int*)alloc((size_t)(GRAPHS + 1) * 4);
    ushort_t* wt2   = (ushort_t*)alloc((size_t)LAYERS * 512 * HID * 2);
    ushort_t* wtC   = (ushort_t*)alloc((size_t)512 * FDIM * 2);
    float* bC0      = (float*)alloc(HID * 4);
    float* bC1      = (float*)alloc(HID * 4);
    float* poolpart = (float*)alloc((size_t)GRAPHS * POOL_P * 512 * 4);

    hipMemsetAsync(cnt, 0, (size_t)N_NODES * 4, stream);
    hipMemsetAsync(fill, 0, (size_t)N_NODES * 4, stream);

    const int nb = (N_NODES + 255) / 256;

    // fused prep: cast_x + count + bounds + wtrans
    k_prep2<<<PREP2_BLOCKS, 256, 0, stream>>>(x, ei, batch, gat_w, res_w,
                                              xb, cnt, rowstart, wt2);
    k_wcomb<<<513, 256, 0, stream>>>(in_w, in_b, res_w, gat_w, res_b,
                                     wtC, bC0, bC1);
    k_scan1<<<nb, 256, 0, stream>>>(cnt, part);
    k_scan2<<<1, 256, 0, stream>>>(part, nb, rowptr);
    k_scan3<<<nb, 256, 0, stream>>>(cnt, part, rowptr);

    const int nw = (N_NODES + 3) / 4;

    // ---- layer 0 GEMM (K=512) + CSR fill fused (fill hides under GEMM) ----
    k_gemm_bf16<FDIM><<<GEMM_BLOCKS + FILL_BLK, 512, 0, stream>>>(
        xb, wtC, bC0, bC1, hresb, xhb, att_src, att_dst, asn, adn, N_NODES,
        ei, rowptr, fill, colv);
    k_agg_ln<<<nw, 256, 0, stream>>>(xhb, asn, adn, rowptr, colv, hresb,
                                     gat_b, ln_g, ln_b, hb);

    // ---- layers 1..2: A = hb, K = 256 (no fill segment) ----
    for (int i = 1; i < LAYERS; ++i) {
        k_gemm_bf16<HID><<<GEMM_BLOCKS, 512, 0, stream>>>(
            hb, wt2 + (size_t)i * 512 * HID,
            res_b + (size_t)i * HID, nullptr, hresb, xhb,
            att_src + (size_t)i * HEADS * CDIM,
            att_dst + (size_t)i * HEADS * CDIM, asn, adn, N_NODES,
            nullptr, nullptr, nullptr, nullptr);
        k_agg_ln<<<nw, 256, 0, stream>>>(xhb, asn, adn, rowptr, colv, hresb,
                                         gat_b + (size_t)i * HID,
                                         ln_g + (size_t)i * HID,
                                         ln_b + (size_t)i * HID, hb);
    }
    dim3 pg(GRAPHS, POOL_P);
    k_pool1<<<pg, 256, 0, stream>>>(hb, rowstart, poolpart);
    k_pool2g<<<GRAPHS, 256, 0, stream>>>(poolpart, rowstart, pool_w, pool_b, out);
}

// Round 18
// 537.081 us; speedup vs baseline: 1.0458x; 1.0089x over previous
//
#include <hip/hip_runtime.h>
#include <math.h>

#define N_NODES 50000
#define E_EDGES 800000
#define E2 (E_EDGES + N_NODES)   // 850000 with self loops
#define M_PAD 50048              // 391 * 128
#define NBM 391                  // M_PAD / 128
#define GEMM_BLOCKS 1568         // 49 chunks * 32
#define FILL_BLK ((E2 + 1023) / 1024)   // 831 (512 thr x 2 edges)
#define FDIM 512
#define HID 256
#define HEADS 8
#define CDIM 32
#define LAYERS 3
#define GRAPHS 64
#define LN_EPS 1e-5f
#define POOL_P 16

typedef unsigned short ushort_t;
typedef __attribute__((ext_vector_type(8))) short short8v;
typedef __attribute__((ext_vector_type(4))) float f32x4;

__device__ __forceinline__ float bf2f(ushort_t u) {
    union { unsigned int i; float f; } v;
    v.i = ((unsigned int)u) << 16;
    return v.f;
}
__device__ __forceinline__ ushort_t f2bf(float f) {
    union { float f; unsigned int u; } v;
    v.f = f;
    unsigned int r = (v.u + 0x7FFFu + ((v.u >> 16) & 1u)) >> 16;
    return (ushort_t)r;
}
__device__ __forceinline__ void gload_lds16(const void* g, void* l) {
    __builtin_amdgcn_global_load_lds(
        (const __attribute__((address_space(1))) void*)g,
        (__attribute__((address_space(3))) void*)l, 16, 0, 0);
}

// ---------------------------------------------------------------- CSR scans
__global__ void k_scan1(const int* __restrict__ cnt, int* __restrict__ part) {
    __shared__ int s[256];
    int t = threadIdx.x;
    int i = blockIdx.x * 256 + t;
    s[t] = (i < N_NODES) ? cnt[i] : 0;
    __syncthreads();
    for (int d = 128; d > 0; d >>= 1) {
        if (t < d) s[t] += s[t + d];
        __syncthreads();
    }
    if (t == 0) part[blockIdx.x] = s[0];
}

__global__ void k_scan2(int* __restrict__ part, int nb, int* __restrict__ rowptr) {
    __shared__ int s[256];
    int t = threadIdx.x;
    int v = (t < nb) ? part[t] : 0;
    s[t] = v;
    __syncthreads();
    for (int d = 1; d < 256; d <<= 1) {
        int x = (t >= d) ? s[t - d] : 0;
        __syncthreads();
        s[t] += x;
        __syncthreads();
    }
    if (t < nb) part[t] = s[t] - v;
    if (t == 255) rowptr[N_NODES] = s[255];
}

__global__ void k_scan3(const int* __restrict__ cnt, const int* __restrict__ part,
                        int* __restrict__ rowptr) {
    __shared__ int s[256];
    int t = threadIdx.x;
    int i = blockIdx.x * 256 + t;
    int v = (i < N_NODES) ? cnt[i] : 0;
    s[t] = v;
    __syncthreads();
    for (int d = 1; d < 256; d <<= 1) {
        int x = (t >= d) ? s[t - d] : 0;
        __syncthreads();
        s[t] += x;
        __syncthreads();
    }
    if (i < N_NODES) rowptr[i] = part[blockIdx.x] + s[t] - v;
}

// ---------------------------------------------------------------- fused prep
// Five block-range segments, all coalesced (R12 lesson: never fuse an
// uncoalesced segment):
//  [0, CAST_BLK)  : x fp32 -> xb bf16 (pad rows zeroed), 8 elems/thread
//  [+GE_BLK)      : edge-count histogram (CSR step 1, device atomics)
//  [+NB_BLK)      : graph row bounds
//  [+WT_BLK)      : wt2 transposes (layers 1..2)
//  [+513)         : wtC combined layer-0 weight + biases (R13 coalesced form)
#define CAST_BLK ((int)((size_t)M_PAD * FDIM / 8 / 256))   // 12512
#define GE_BLK ((E2 + 255) / 256)                          // 3321
#define NB_BLK ((N_NODES + 255) / 256)                     // 196
#define MAT_ELEMS (HID * HID)
#define WT_TOTAL (2 * (LAYERS - 1) * MAT_ELEMS)
#define WT_BLK (WT_TOTAL / 256)                            // 1024
#define PREP2_BLOCKS (CAST_BLK + GE_BLK + NB_BLK + WT_BLK + 513)

__global__ __launch_bounds__(256) void k_prep2(const float* __restrict__ x,
                                               const int* __restrict__ ei,
                                               const int* __restrict__ batch,
                                               const float* __restrict__ in_w,
                                               const float* __restrict__ in_b,
                                               const float* __restrict__ gat_w,
                                               const float* __restrict__ res_w,
                                               const float* __restrict__ res_b,
                                               ushort_t* __restrict__ xb,
                                               int* __restrict__ cnt,
                                               int* __restrict__ rowstart,
                                               ushort_t* __restrict__ wt2,
                                               ushort_t* __restrict__ wtC,
                                               float* __restrict__ bC0,
                                               float* __restrict__ bC1) {
    int bid = blockIdx.x;
    if (bid < CAST_BLK) {
        long long i8 = ((long long)bid * 256 + threadIdx.x) * 8;
        int row = (int)(i8 >> 9);
        ushort_t o[8];
        if (row < N_NODES) {
            const float* p = x + i8;
            #pragma unroll
            for (int j = 0; j < 8; ++j) o[j] = f2bf(p[j]);
        } else {
            #pragma unroll
            for (int j = 0; j < 8; ++j) o[j] = 0;
        }
        *(short8v*)(xb + i8) = *(short8v*)o;
        return;
    }
    bid -= CAST_BLK;
    if (bid < GE_BLK) {
        int e = bid * 256 + threadIdx.x;
        if (e >= E2) return;
        int dst = (e < E_EDGES) ? ei[E_EDGES + e] : (e - E_EDGES);
        atomicAdd(&cnt[dst], 1);
        return;
    }
    bid -= GE_BLK;
    if (bid < NB_BLK) {
        int n = bid * 256 + threadIdx.x;
        if (n >= N_NODES) return;
        int b = batch[n];
        int bp = (n == 0) ? -1 : batch[n - 1];
        for (int g = bp + 1; g <= b; ++g) rowstart[g] = n;
        if (n == N_NODES - 1) {
            for (int g = b + 1; g <= GRAPHS; ++g) rowstart[g] = N_NODES;
        }
        return;
    }
    bid -= NB_BLK;
    if (bid < WT_BLK) {
        int r = bid * 256 + threadIdx.x;
        int mat = r >> 16;            // 0..3
        int layer = 1 + (mat >> 1);
        int isgat = mat & 1;
        int within = r & 65535;
        int k = within >> 8, n = within & 255;
        const float* W = (isgat ? gat_w : res_w) + (size_t)layer * MAT_ELEMS;
        wt2[(size_t)layer * 512 * HID + (size_t)(isgat * 256 + n) * HID + k] =
            f2bf(W[within]);
        return;
    }
    bid -= WT_BLK;
    // ---- wcomb segment (R13 coalesced form) ----
    {
        __shared__ float irow[HID];
        const int f = bid;                               // 0..512
        const int n = threadIdx.x;
        irow[n] = (f == 512) ? in_b[n] : in_w[(size_t)f * HID + n];
        __syncthreads();
        float s0 = 0.f, s1 = 0.f;
        #pragma unroll 4
        for (int k = 0; k < HID; ++k) {
            float iv = irow[k];
            s0 += iv * bf2f(f2bf(res_w[(size_t)k * HID + n]));
            s1 += iv * bf2f(f2bf(gat_w[(size_t)k * HID + n]));
        }
        if (f == 512) {
            bC0[n] = s0 + res_b[n];
            bC1[n] = s1;
        } else {
            wtC[(size_t)n * FDIM + f] = f2bf(s0);            // res half
            wtC[(size_t)(256 + n) * FDIM + f] = f2bf(s1);    // gat half
        }
    }
}

// ---------------------------------------------------------------- bf16 MFMA GEMM (+ fused CSR fill)
// 8-wave (512 thr), 128x128 tile, BK=32, 16KB LDS single buffer (R8/R10
// measured-best), compiler-scheduled barriers, 1D grid with XCD swizzle
// (R10-verified). Blocks >= GEMM_BLOCKS run the CSR fill segment, hidden
// under the latency-bound GEMM (R17-verified: net ~+10us).
template<int K>
__global__ __launch_bounds__(512) void k_gemm_bf16(const ushort_t* __restrict__ A,
                                                   const ushort_t* __restrict__ BT,
                                                   const float* __restrict__ bias0,
                                                   const float* __restrict__ bias1,
                                                   ushort_t* __restrict__ C0,
                                                   ushort_t* __restrict__ C1,
                                                   const float* __restrict__ a_src,
                                                   const float* __restrict__ a_dst,
                                                   float* __restrict__ asn,
                                                   float* __restrict__ adn, int M,
                                                   const int* __restrict__ ei,
                                                   const int* __restrict__ rowptr,
                                                   int* __restrict__ fillc,
                                                   int* __restrict__ colv) {
    const int L = blockIdx.x;
    if (L >= GEMM_BLOCKS) {
        // ---- CSR fill segment ----
        int e0 = (L - GEMM_BLOCKS) * 1024 + threadIdx.x;
        #pragma unroll
        for (int j = 0; j < 2; ++j) {
            int e = e0 + j * 512;
            if (e < E2) {
                int src, dst;
                if (e < E_EDGES) { src = ei[e]; dst = ei[E_EDGES + e]; }
                else             { src = dst = e - E_EDGES; }
                int pos = atomicAdd(&fillc[dst], 1);
                colv[rowptr[dst] + pos] = src;
            }
        }
        return;
    }
    const int chunk = L >> 5, wrd = L & 31;
    const int bmi = chunk * 8 + (wrd & 7);
    if (bmi >= NBM) return;
    const int bm = bmi * 128;
    const int bn = (wrd >> 3) * 128;

    __shared__ char lds[16384] __attribute__((aligned(16)));
    const int t = threadIdx.x, w = t >> 6, l = t & 63;
    const int wr = w & 3, wc = w >> 2;

    const int arow = t >> 2;
    const int aslot = (t & 3) ^ ((arow >> 1) & 3);
    const ushort_t* pa = A + (size_t)(bm + arow) * K + aslot * 8;
    const ushort_t* pb = BT + (size_t)(bn + arow) * K + aslot * 8;
    char* la = lds + w * 1024;
    char* lb = lds + 8192 + w * 1024;

    int aoff[2], boff[4];
    const int kb = l >> 4;
    #pragma unroll
    for (int mi = 0; mi < 2; ++mi) {
        int r = wr * 32 + mi * 16 + (l & 15);
        aoff[mi] = r * 64 + ((kb ^ ((r >> 1) & 3)) << 4);
    }
    #pragma unroll
    for (int ni = 0; ni < 4; ++ni) {
        int c = wc * 64 + ni * 16 + (l & 15);
        boff[ni] = 8192 + c * 64 + ((kb ^ ((c >> 1) & 3)) << 4);
    }

    f32x4 acc[2][4] = {};
    for (int k0 = 0; k0 < K; k0 += 32) {
        gload_lds16(pa + k0, la);
        gload_lds16(pb + k0, lb);
        __syncthreads();
        short8v a[2], b[4];
        #pragma unroll
        for (int mi = 0; mi < 2; ++mi) a[mi] = *(const short8v*)(lds + aoff[mi]);
        #pragma unroll
        for (int ni = 0; ni < 4; ++ni) b[ni] = *(const short8v*)(lds + boff[ni]);
        #pragma unroll
        for (int mi = 0; mi < 2; ++mi)
            #pragma unroll
            for (int ni = 0; ni < 4; ++ni)
                acc[mi][ni] = __builtin_amdgcn_mfma_f32_16x16x32_bf16(
                    a[mi], b[ni], acc[mi][ni], 0, 0, 0);
        __syncthreads();
    }

    ushort_t* C = (bn < 256) ? C0 : C1;
    const float* bias = (bn < 256) ? bias0 : bias1;
    const int cb = (bn < 256) ? bn : bn - 256;
    #pragma unroll
    for (int mi = 0; mi < 2; ++mi) {
        int row = bm + wr * 32 + mi * 16 + (l >> 4) * 4;
        #pragma unroll
        for (int ni = 0; ni < 4; ++ni) {
            int col = cb + wc * 64 + ni * 16 + (l & 15);
            float bv = bias ? bias[col] : 0.f;
            #pragma unroll
            for (int r = 0; r < 4; ++r) {
                if (row + r < M)
                    C[(size_t)(row + r) * HID + col] = f2bf(acc[mi][ni][r] + bv);
            }
        }
    }

    if (asn && bn >= 256) {
        const int cbase = bn - 256;                    // 0 or 128
        #pragma unroll
        for (int mi = 0; mi < 2; ++mi) {
            int row = bm + wr * 32 + mi * 16 + (l >> 4) * 4;
            #pragma unroll
            for (int p = 0; p < 2; ++p) {
                int c0 = cbase + wc * 64 + (2 * p) * 16 + (l & 15);
                int c1c = c0 + 16;
                int head = c0 >> 5;
                float b1a = bias1 ? bias1[c0] : 0.f;
                float b1b = bias1 ? bias1[c1c] : 0.f;
                float as0 = a_src[c0], as1 = a_src[c1c];
                float ad0 = a_dst[c0], ad1 = a_dst[c1c];
                float vs[4], vd[4];
                #pragma unroll
                for (int r = 0; r < 4; ++r) {
                    float x0 = acc[mi][2 * p][r] + b1a;
                    float x1 = acc[mi][2 * p + 1][r] + b1b;
                    vs[r] = x0 * as0 + x1 * as1;
                    vd[r] = x0 * ad0 + x1 * ad1;
                }
                #pragma unroll
                for (int d = 1; d < 16; d <<= 1) {
                    #pragma unroll
                    for (int r = 0; r < 4; ++r) {
                        vs[r] += __shfl_xor(vs[r], d);
                        vd[r] += __shfl_xor(vd[r], d);
                    }
                }
                if ((l & 15) == 0) {
                    #pragma unroll
                    for (int r = 0; r < 4; ++r) {
                        if (row + r < N_NODES) {
                            asn[(row + r) * HEADS + head] = vs[r];
                            adn[(row + r) * HEADS + head] = vd[r];
                        }
                    }
                }
            }
        }
    }
}

// ---------------------------------------------------------------- aggregation + residual + LN + ReLU
__global__ __launch_bounds__(256) void k_agg_ln(const ushort_t* __restrict__ xhb,
                                                const float* __restrict__ asn,
                                                const float* __restrict__ adn,
                                                const int* __restrict__ rowptr,
                                                const int* __restrict__ colv,
                                                const ushort_t* __restrict__ hresb,
                                                const float* __restrict__ gb,
                                                const float* __restrict__ g,
                                                const float* __restrict__ b,
                                                ushort_t* __restrict__ hb) {
    const int wave = threadIdx.x >> 6, lane = threadIdx.x & 63;
    const int n = blockIdx.x * 4 + wave;
    if (n >= N_NODES) return;
    const int half = lane >> 5;
    const int lh = lane & 31;
    const int head = lh >> 2;
    const int ch0 = lh * 8;
    const float adn_h = adn[n * HEADS + head];
    const int j0 = rowptr[n], j1 = rowptr[n + 1];

    float acc[8] = {};
    float den = 0.f;
    int base = j0;
    for (; base + 8 <= j1; base += 8) {
        int idx[4];
        #pragma unroll
        for (int q = 0; q < 4; ++q) idx[q] = colv[base + 2 * q + half];
        short8v u[4];
        #pragma unroll
        for (int q = 0; q < 4; ++q)
            u[q] = *(const short8v*)(xhb + (size_t)idx[q] * HID + ch0);
        float p[4];
        #pragma unroll
        for (int q = 0; q < 4; ++q) {
            float e = asn[idx[q] * HEADS + head] + adn_h;
            e = (e > 0.f) ? e : 0.2f * e;
            p[q] = __expf(e);
        }
        #pragma unroll
        for (int q = 0; q < 4; ++q) {
            den += p[q];
            #pragma unroll
            for (int c = 0; c < 8; ++c)
                acc[c] += p[q] * bf2f((ushort_t)u[q][c]);
        }
    }
    for (; base < j1; base += 2) {
        bool valid = (base + half) < j1;
        int s = valid ? colv[base + half] : n;
        short8v u = *(const short8v*)(xhb + (size_t)s * HID + ch0);
        float e = asn[s * HEADS + head] + adn_h;
        e = (e > 0.f) ? e : 0.2f * e;
        float p = valid ? __expf(e) : 0.f;
        den += p;
        #pragma unroll
        for (int c = 0; c < 8; ++c)
            acc[c] += p * bf2f((ushort_t)u[c]);
    }
    den += __shfl_xor(den, 32);
    #pragma unroll
    for (int c = 0; c < 8; ++c) acc[c] += __shfl_xor(acc[c], 32);

    const float inv = 1.f / (den + 1e-16f);
    short8v hr = *(const short8v*)(hresb + (size_t)n * HID + ch0);
    float4 gbA = *(const float4*)(gb + ch0);
    float4 gbB = *(const float4*)(gb + ch0 + 4);
    float v[8];
    #pragma unroll
    for (int c = 0; c < 8; ++c) {
        float gbv = (c < 4) ? ((const float*)&gbA)[c] : ((const float*)&gbB)[c - 4];
        v[c] = acc[c] * inv + bf2f((ushort_t)hr[c]) + gbv;
    }
    float s = 0.f;
    #pragma unroll
    for (int c = 0; c < 8; ++c) s += v[c];
    #pragma unroll
    for (int d = 1; d < 32; d <<= 1) s += __shfl_xor(s, d);
    const float mu = s * (1.f / HID);
    float q = 0.f;
    #pragma unroll
    for (int c = 0; c < 8; ++c) {
        v[c] -= mu;
        q += v[c] * v[c];
    }
    #pragma unroll
    for (int d = 1; d < 32; d <<= 1) q += __shfl_xor(q, d);
    const float rstd = rsqrtf(q * (1.f / HID) + LN_EPS);
    float4 gA = *(const float4*)(g + ch0);
    float4 gB = *(const float4*)(g + ch0 + 4);
    float4 bA = *(const float4*)(b + ch0);
    float4 bB = *(const float4*)(b + ch0 + 4);
    ushort_t o[8];
    #pragma unroll
    for (int c = 0; c < 8; ++c) {
        float gv = (c < 4) ? ((const float*)&gA)[c] : ((const float*)&gB)[c - 4];
        float bv = (c < 4) ? ((const float*)&bA)[c] : ((const float*)&bB)[c - 4];
        o[c] = f2bf(fmaxf(v[c] * rstd * gv + bv, 0.f));
    }
    if (half == 0)
        *(short8v*)(hb + (size_t)n * HID + ch0) = *(short8v*)o;
}

// ---------------------------------------------------------------- pooling
__global__ __launch_bounds__(256) void k_pool1(const ushort_t* __restrict__ hb,
                                               const int* __restrict__ rowstart,
                                               float* __restrict__ part) {
    int g = blockIdx.x, p = blockIdx.y, c = threadIdx.x;
    int s0 = rowstart[g], s1 = rowstart[g + 1];
    float sum = 0.f, mx = -INFINITY;
    for (int n = s0 + p; n < s1; n += POOL_P) {
        float v = bf2f(hb[(size_t)n * HID + c]);
        sum += v;
        mx = fmaxf(mx, v);
    }
    float* pp = part + (size_t)(g * POOL_P + p) * 512;
    pp[c] = sum;
    pp[256 + c] = mx;
}

__global__ __launch_bounds__(256) void k_pool2g(const float* __restrict__ part,
                                                const int* __restrict__ rowstart,
                                                const float* __restrict__ W,
                                                const float* __restrict__ bias,
                                                float* __restrict__ out) {
    __shared__ float hc[512];
    int g = blockIdx.x, c = threadIdx.x;
    float sum = 0.f, mx = -INFINITY;
    for (int p = 0; p < POOL_P; ++p) {
        const float* pp = part + (size_t)(g * POOL_P + p) * 512;
        sum += pp[c];
        mx = fmaxf(mx, pp[256 + c]);
    }
    float cntf = (float)(rowstart[g + 1] - rowstart[g]);
    hc[c] = sum / fmaxf(cntf, 1.f);
    hc[256 + c] = mx;
    __syncthreads();
    float acc = bias[c];
    #pragma unroll 8
    for (int k = 0; k < 2 * HID; ++k)
        acc += hc[k] * W[(size_t)k * HID + c];
    out[(size_t)g * HID + c] = fmaxf(acc, 0.f);
}

// ---------------------------------------------------------------- launch
extern "C" void kernel_launch(void* const* d_in, const int* in_sizes, int n_in,
                              void* d_out, int out_size, void* d_ws, size_t ws_size,
                              hipStream_t stream) {
    const float* x       = (const float*)d_in[0];
    const int*   ei      = (const int*)d_in[1];
    const int*   batch   = (const int*)d_in[2];
    const float* in_w    = (const float*)d_in[3];
    const float* in_b    = (const float*)d_in[4];
    const float* gat_w   = (const float*)d_in[5];
    const float* att_src = (const float*)d_in[6];
    const float* att_dst = (const float*)d_in[7];
    const float* gat_b   = (const float*)d_in[8];
    const float* res_w   = (const float*)d_in[9];
    const float* res_b   = (const float*)d_in[10];
    const float* ln_g    = (const float*)d_in[11];
    const float* ln_b    = (const float*)d_in[12];
    const float* pool_w  = (const float*)d_in[13];
    const float* pool_b  = (const float*)d_in[14];
    float* out = (float*)d_out;

    char* ws = (char*)d_ws;
    size_t off = 0;
    auto alloc = [&](size_t bytes) -> char* {
        char* p = ws + off;
        off = (off + bytes + 255) & ~(size_t)255;
        return p;
    };
    ushort_t* xb    = (ushort_t*)alloc((size_t)M_PAD * FDIM * 2);
    ushort_t* hb    = (ushort_t*)alloc((size_t)M_PAD * HID * 2);
    ushort_t* xhb   = (ushort_t*)alloc((size_t)M_PAD * HID * 2);
    ushort_t* hresb = (ushort_t*)alloc((size_t)M_PAD * HID * 2);
    float* asn      = (float*)alloc((size_t)N_NODES * HEADS * 4);
    float* adn      = (float*)alloc((size_t)N_NODES * HEADS * 4);
    int*   cnt      = (int*)alloc((size_t)N_NODES * 4);
    int*   fill     = (int*)alloc((size_t)N_NODES * 4);
    int*   rowptr   = (int*)alloc((size_t)(N_NODES + 1) * 4);
    int*   colv     = (int*)alloc((size_t)E2 * 4);
    int*   part     = (int*)alloc(256 * 4);
    int*   rowstart = (int*)alloc((size_t)(GRAPHS + 1) * 4);
    ushort_t* wt2   = (ushort_t*)alloc((size_t)LAYERS * 512 * HID * 2);
    ushort_t* wtC   = (ushort_t*)alloc((size_t)512 * FDIM * 2);
    float* bC0      = (float*)alloc(HID * 4);
    float* bC1      = (float*)alloc(HID * 4);
    float* poolpart = (float*)alloc((size_t)GRAPHS * POOL_P * 512 * 4);

    hipMemsetAsync(cnt, 0, (size_t)N_NODES * 4, stream);
    hipMemsetAsync(fill, 0, (size_t)N_NODES * 4, stream);

    const int nb = (N_NODES + 255) / 256;

    // fused prep: cast_x + count + bounds + wtrans + wcomb (all coalesced)
    k_prep2<<<PREP2_BLOCKS, 256, 0, stream>>>(x, ei, batch, in_w, in_b,
                                              gat_w, res_w, res_b,
                                              xb, cnt, rowstart, wt2,
                                              wtC, bC0, bC1);
    k_scan1<<<nb, 256, 0, stream>>>(cnt, part);
    k_scan2<<<1, 256, 0, stream>>>(part, nb, rowptr);
    k_scan3<<<nb, 256, 0, stream>>>(cnt, part, rowptr);

    const int nw = (N_NODES + 3) / 4;

    // ---- layer 0 GEMM (K=512) + CSR fill fused ----
    k_gemm_bf16<FDIM><<<GEMM_BLOCKS + FILL_BLK, 512, 0, stream>>>(
        xb, wtC, bC0, bC1, hresb, xhb, att_src, att_dst, asn, adn, N_NODES,
        ei, rowptr, fill, colv);
    k_agg_ln<<<nw, 256, 0, stream>>>(xhb, asn, adn, rowptr, colv, hresb,
                                     gat_b, ln_g, ln_b, hb);

    // ---- layers 1..2: A = hb, K = 256 (no fill segment) ----
    for (int i = 1; i < LAYERS; ++i) {
        k_gemm_bf16<HID><<<GEMM_BLOCKS, 512, 0, stream>>>(
            hb, wt2 + (size_t)i * 512 * HID,
            res_b + (size_t)i * HID, nullptr, hresb, xhb,
            att_src + (size_t)i * HEADS * CDIM,
            att_dst + (size_t)i * HEADS * CDIM, asn, adn, N_NODES,
            nullptr, nullptr, nullptr, nullptr);
        k_agg_ln<<<nw, 256, 0, stream>>>(xhb, asn, adn, rowptr, colv, hresb,
                                         gat_b + (size_t)i * HID,
                                         ln_g + (size_t)i * HID,
                                         ln_b + (size_t)i * HID, hb);
    }
    dim3 pg(GRAPHS, POOL_P);
    k_pool1<<<pg, 256, 0, stream>>>(hb, rowstart, poolpart);
    k_pool2g<<<GRAPHS, 256, 0, stream>>>(poolpart, rowstart, pool_w, pool_b, out);
}

// Round 19
// 530.595 us; speedup vs baseline: 1.0586x; 1.0122x over previous
//
#include <hip/hip_runtime.h>
#include <math.h>

#define N_NODES 50000
#define E_EDGES 800000
#define E2 (E_EDGES + N_NODES)   // 850000 with self loops
#define M_PAD 50048              // 391 * 128
#define NBM 391                  // M_PAD / 128
#define GEMM_BLOCKS 1568         // 49 chunks * 32
#define FILL_BLK ((E2 + 1023) / 1024)   // 831 (512 thr x 2 edges)
#define FDIM 512
#define HID 256
#define HEADS 8
#define CDIM 32
#define LAYERS 3
#define GRAPHS 64
#define LN_EPS 1e-5f
#define POOL_P 16

typedef unsigned short ushort_t;
typedef __attribute__((ext_vector_type(8))) short short8v;
typedef __attribute__((ext_vector_type(4))) float f32x4;

__device__ __forceinline__ float bf2f(ushort_t u) {
    union { unsigned int i; float f; } v;
    v.i = ((unsigned int)u) << 16;
    return v.f;
}
__device__ __forceinline__ ushort_t f2bf(float f) {
    union { float f; unsigned int u; } v;
    v.f = f;
    unsigned int r = (v.u + 0x7FFFu + ((v.u >> 16) & 1u)) >> 16;
    return (ushort_t)r;
}
__device__ __forceinline__ void gload_lds16(const void* g, void* l) {
    __builtin_amdgcn_global_load_lds(
        (const __attribute__((address_space(1))) void*)g,
        (__attribute__((address_space(3))) void*)l, 16, 0, 0);
}

// ---------------------------------------------------------------- CSR scans
__global__ void k_scan1(const int* __restrict__ cnt, int* __restrict__ part) {
    __shared__ int s[256];
    int t = threadIdx.x;
    int i = blockIdx.x * 256 + t;
    s[t] = (i < N_NODES) ? cnt[i] : 0;
    __syncthreads();
    for (int d = 128; d > 0; d >>= 1) {
        if (t < d) s[t] += s[t + d];
        __syncthreads();
    }
    if (t == 0) part[blockIdx.x] = s[0];
}

__global__ void k_scan2(int* __restrict__ part, int nb, int* __restrict__ rowptr) {
    __shared__ int s[256];
    int t = threadIdx.x;
    int v = (t < nb) ? part[t] : 0;
    s[t] = v;
    __syncthreads();
    for (int d = 1; d < 256; d <<= 1) {
        int x = (t >= d) ? s[t - d] : 0;
        __syncthreads();
        s[t] += x;
        __syncthreads();
    }
    if (t < nb) part[t] = s[t] - v;
    if (t == 255) rowptr[N_NODES] = s[255];
}

__global__ void k_scan3(const int* __restrict__ cnt, const int* __restrict__ part,
                        int* __restrict__ rowptr) {
    __shared__ int s[256];
    int t = threadIdx.x;
    int i = blockIdx.x * 256 + t;
    int v = (i < N_NODES) ? cnt[i] : 0;
    s[t] = v;
    __syncthreads();
    for (int d = 1; d < 256; d <<= 1) {
        int x = (t >= d) ? s[t - d] : 0;
        __syncthreads();
        s[t] += x;
        __syncthreads();
    }
    if (i < N_NODES) rowptr[i] = part[blockIdx.x] + s[t] - v;
}

// ---------------------------------------------------------------- fused prep
// LPT segment order (R18 post-mortem: wcomb at the tail serialized ~27us):
//  [0, 513)       : wcomb -- LONGEST per-block work, scheduled FIRST
//  [+CAST_BLK)    : x fp32 -> xb bf16 (pad rows zeroed), 8 elems/thread
//  [+GE_BLK)      : edge-count histogram (device atomics)
//  [+NB_BLK)      : graph row bounds
//  [+WT_BLK)      : wt2 transposes (layers 1..2)
#define CAST_BLK ((int)((size_t)M_PAD * FDIM / 8 / 256))   // 12512
#define GE_BLK ((E2 + 255) / 256)                          // 3321
#define NB_BLK ((N_NODES + 255) / 256)                     // 196
#define MAT_ELEMS (HID * HID)
#define WT_TOTAL (2 * (LAYERS - 1) * MAT_ELEMS)
#define WT_BLK (WT_TOTAL / 256)                            // 1024
#define PREP2_BLOCKS (513 + CAST_BLK + GE_BLK + NB_BLK + WT_BLK)

__global__ __launch_bounds__(256) void k_prep2(const float* __restrict__ x,
                                               const int* __restrict__ ei,
                                               const int* __restrict__ batch,
                                               const float* __restrict__ in_w,
                                               const float* __restrict__ in_b,
                                               const float* __restrict__ gat_w,
                                               const float* __restrict__ res_w,
                                               const float* __restrict__ res_b,
                                               ushort_t* __restrict__ xb,
                                               int* __restrict__ cnt,
                                               int* __restrict__ rowstart,
                                               ushort_t* __restrict__ wt2,
                                               ushort_t* __restrict__ wtC,
                                               float* __restrict__ bC0,
                                               float* __restrict__ bC1) {
    int bid = blockIdx.x;
    if (bid < 513) {
        // ---- wcomb segment (R13 coalesced form), scheduled first ----
        __shared__ float irow[HID];
        const int f = bid;                               // 0..512
        const int n = threadIdx.x;
        irow[n] = (f == 512) ? in_b[n] : in_w[(size_t)f * HID + n];
        __syncthreads();
        float s0 = 0.f, s1 = 0.f;
        #pragma unroll 4
        for (int k = 0; k < HID; ++k) {
            float iv = irow[k];
            s0 += iv * bf2f(f2bf(res_w[(size_t)k * HID + n]));
            s1 += iv * bf2f(f2bf(gat_w[(size_t)k * HID + n]));
        }
        if (f == 512) {
            bC0[n] = s0 + res_b[n];
            bC1[n] = s1;
        } else {
            wtC[(size_t)n * FDIM + f] = f2bf(s0);            // res half
            wtC[(size_t)(256 + n) * FDIM + f] = f2bf(s1);    // gat half
        }
        return;
    }
    bid -= 513;
    if (bid < CAST_BLK) {
        long long i8 = ((long long)bid * 256 + threadIdx.x) * 8;
        int row = (int)(i8 >> 9);
        ushort_t o[8];
        if (row < N_NODES) {
            const float* p = x + i8;
            #pragma unroll
            for (int j = 0; j < 8; ++j) o[j] = f2bf(p[j]);
        } else {
            #pragma unroll
            for (int j = 0; j < 8; ++j) o[j] = 0;
        }
        *(short8v*)(xb + i8) = *(short8v*)o;
        return;
    }
    bid -= CAST_BLK;
    if (bid < GE_BLK) {
        int e = bid * 256 + threadIdx.x;
        if (e >= E2) return;
        int dst = (e < E_EDGES) ? ei[E_EDGES + e] : (e - E_EDGES);
        atomicAdd(&cnt[dst], 1);
        return;
    }
    bid -= GE_BLK;
    if (bid < NB_BLK) {
        int n = bid * 256 + threadIdx.x;
        if (n >= N_NODES) return;
        int b = batch[n];
        int bp = (n == 0) ? -1 : batch[n - 1];
        for (int g = bp + 1; g <= b; ++g) rowstart[g] = n;
        if (n == N_NODES - 1) {
            for (int g = b + 1; g <= GRAPHS; ++g) rowstart[g] = N_NODES;
        }
        return;
    }
    bid -= NB_BLK;
    {
        int r = bid * 256 + threadIdx.x;
        int mat = r >> 16;            // 0..3
        int layer = 1 + (mat >> 1);
        int isgat = mat & 1;
        int within = r & 65535;
        int k = within >> 8, n = within & 255;
        const float* W = (isgat ? gat_w : res_w) + (size_t)layer * MAT_ELEMS;
        wt2[(size_t)layer * 512 * HID + (size_t)(isgat * 256 + n) * HID + k] =
            f2bf(W[within]);
    }
}

// ---------------------------------------------------------------- bf16 MFMA GEMM (+ fused CSR fill)
// 8-wave (512 thr), 128x128 tile, BK=32, 16KB LDS single buffer (R8/R10
// measured-best), compiler-scheduled barriers, 1D grid with XCD swizzle
// (R10-verified). Blocks >= GEMM_BLOCKS run the CSR fill segment, hidden
// under the latency-bound GEMM (R17-verified: net ~+10us).
template<int K>
__global__ __launch_bounds__(512) void k_gemm_bf16(const ushort_t* __restrict__ A,
                                                   const ushort_t* __restrict__ BT,
                                                   const float* __restrict__ bias0,
                                                   const float* __restrict__ bias1,
                                                   ushort_t* __restrict__ C0,
                                                   ushort_t* __restrict__ C1,
                                                   const float* __restrict__ a_src,
                                                   const float* __restrict__ a_dst,
                                                   float* __restrict__ asn,
                                                   float* __restrict__ adn, int M,
                                                   const int* __restrict__ ei,
                                                   const int* __restrict__ rowptr,
                                                   int* __restrict__ fillc,
                                                   int* __restrict__ colv) {
    const int L = blockIdx.x;
    if (L >= GEMM_BLOCKS) {
        // ---- CSR fill segment ----
        int e0 = (L - GEMM_BLOCKS) * 1024 + threadIdx.x;
        #pragma unroll
        for (int j = 0; j < 2; ++j) {
            int e = e0 + j * 512;
            if (e < E2) {
                int src, dst;
                if (e < E_EDGES) { src = ei[e]; dst = ei[E_EDGES + e]; }
                else             { src = dst = e - E_EDGES; }
                int pos = atomicAdd(&fillc[dst], 1);
                colv[rowptr[dst] + pos] = src;
            }
        }
        return;
    }
    const int chunk = L >> 5, wrd = L & 31;
    const int bmi = chunk * 8 + (wrd & 7);
    if (bmi >= NBM) return;
    const int bm = bmi * 128;
    const int bn = (wrd >> 3) * 128;

    __shared__ char lds[16384] __attribute__((aligned(16)));
    const int t = threadIdx.x, w = t >> 6, l = t & 63;
    const int wr = w & 3, wc = w >> 2;

    const int arow = t >> 2;
    const int aslot = (t & 3) ^ ((arow >> 1) & 3);
    const ushort_t* pa = A + (size_t)(bm + arow) * K + aslot * 8;
    const ushort_t* pb = BT + (size_t)(bn + arow) * K + aslot * 8;
    char* la = lds + w * 1024;
    char* lb = lds + 8192 + w * 1024;

    int aoff[2], boff[4];
    const int kb = l >> 4;
    #pragma unroll
    for (int mi = 0; mi < 2; ++mi) {
        int r = wr * 32 + mi * 16 + (l & 15);
        aoff[mi] = r * 64 + ((kb ^ ((r >> 1) & 3)) << 4);
    }
    #pragma unroll
    for (int ni = 0; ni < 4; ++ni) {
        int c = wc * 64 + ni * 16 + (l & 15);
        boff[ni] = 8192 + c * 64 + ((kb ^ ((c >> 1) & 3)) << 4);
    }

    f32x4 acc[2][4] = {};
    for (int k0 = 0; k0 < K; k0 += 32) {
        gload_lds16(pa + k0, la);
        gload_lds16(pb + k0, lb);
        __syncthreads();
        short8v a[2], b[4];
        #pragma unroll
        for (int mi = 0; mi < 2; ++mi) a[mi] = *(const short8v*)(lds + aoff[mi]);
        #pragma unroll
        for (int ni = 0; ni < 4; ++ni) b[ni] = *(const short8v*)(lds + boff[ni]);
        #pragma unroll
        for (int mi = 0; mi < 2; ++mi)
            #pragma unroll
            for (int ni = 0; ni < 4; ++ni)
                acc[mi][ni] = __builtin_amdgcn_mfma_f32_16x16x32_bf16(
                    a[mi], b[ni], acc[mi][ni], 0, 0, 0);
        __syncthreads();
    }

    ushort_t* C = (bn < 256) ? C0 : C1;
    const float* bias = (bn < 256) ? bias0 : bias1;
    const int cb = (bn < 256) ? bn : bn - 256;
    #pragma unroll
    for (int mi = 0; mi < 2; ++mi) {
        int row = bm + wr * 32 + mi * 16 + (l >> 4) * 4;
        #pragma unroll
        for (int ni = 0; ni < 4; ++ni) {
            int col = cb + wc * 64 + ni * 16 + (l & 15);
            float bv = bias ? bias[col] : 0.f;
            #pragma unroll
            for (int r = 0; r < 4; ++r) {
                if (row + r < M)
                    C[(size_t)(row + r) * HID + col] = f2bf(acc[mi][ni][r] + bv);
            }
        }
    }

    if (asn && bn >= 256) {
        const int cbase = bn - 256;                    // 0 or 128
        #pragma unroll
        for (int mi = 0; mi < 2; ++mi) {
            int row = bm + wr * 32 + mi * 16 + (l >> 4) * 4;
            #pragma unroll
            for (int p = 0; p < 2; ++p) {
                int c0 = cbase + wc * 64 + (2 * p) * 16 + (l & 15);
                int c1c = c0 + 16;
                int head = c0 >> 5;
                float b1a = bias1 ? bias1[c0] : 0.f;
                float b1b = bias1 ? bias1[c1c] : 0.f;
                float as0 = a_src[c0], as1 = a_src[c1c];
                float ad0 = a_dst[c0], ad1 = a_dst[c1c];
                float vs[4], vd[4];
                #pragma unroll
                for (int r = 0; r < 4; ++r) {
                    float x0 = acc[mi][2 * p][r] + b1a;
                    float x1 = acc[mi][2 * p + 1][r] + b1b;
                    vs[r] = x0 * as0 + x1 * as1;
                    vd[r] = x0 * ad0 + x1 * ad1;
                }
                #pragma unroll
                for (int d = 1; d < 16; d <<= 1) {
                    #pragma unroll
                    for (int r = 0; r < 4; ++r) {
                        vs[r] += __shfl_xor(vs[r], d);
                        vd[r] += __shfl_xor(vd[r], d);
                    }
                }
                if ((l & 15) == 0) {
                    #pragma unroll
                    for (int r = 0; r < 4; ++r) {
                        if (row + r < N_NODES) {
                            asn[(row + r) * HEADS + head] = vs[r];
                            adn[(row + r) * HEADS + head] = vd[r];
                        }
                    }
                }
            }
        }
    }
}

// ---------------------------------------------------------------- aggregation + residual + LN + ReLU
__global__ __launch_bounds__(256) void k_agg_ln(const ushort_t* __restrict__ xhb,
                                                const float* __restrict__ asn,
                                                const float* __restrict__ adn,
                                                const int* __restrict__ rowptr,
                                                const int* __restrict__ colv,
                                                const ushort_t* __restrict__ hresb,
                                                const float* __restrict__ gb,
                                                const float* __restrict__ g,
                                                const float* __restrict__ b,
                                                ushort_t* __restrict__ hb) {
    const int wave = threadIdx.x >> 6, lane = threadIdx.x & 63;
    const int n = blockIdx.x * 4 + wave;
    if (n >= N_NODES) return;
    const int half = lane >> 5;
    const int lh = lane & 31;
    const int head = lh >> 2;
    const int ch0 = lh * 8;
    const float adn_h = adn[n * HEADS + head];
    const int j0 = rowptr[n], j1 = rowptr[n + 1];

    float acc[8] = {};
    float den = 0.f;
    int base = j0;
    for (; base + 8 <= j1; base += 8) {
        int idx[4];
        #pragma unroll
        for (int q = 0; q < 4; ++q) idx[q] = colv[base + 2 * q + half];
        short8v u[4];
        #pragma unroll
        for (int q = 0; q < 4; ++q)
            u[q] = *(const short8v*)(xhb + (size_t)idx[q] * HID + ch0);
        float p[4];
        #pragma unroll
        for (int q = 0; q < 4; ++q) {
            float e = asn[idx[q] * HEADS + head] + adn_h;
            e = (e > 0.f) ? e : 0.2f * e;
            p[q] = __expf(e);
        }
        #pragma unroll
        for (int q = 0; q < 4; ++q) {
            den += p[q];
            #pragma unroll
            for (int c = 0; c < 8; ++c)
                acc[c] += p[q] * bf2f((ushort_t)u[q][c]);
        }
    }
    for (; base < j1; base += 2) {
        bool valid = (base + half) < j1;
        int s = valid ? colv[base + half] : n;
        short8v u = *(const short8v*)(xhb + (size_t)s * HID + ch0);
        float e = asn[s * HEADS + head] + adn_h;
        e = (e > 0.f) ? e : 0.2f * e;
        float p = valid ? __expf(e) : 0.f;
        den += p;
        #pragma unroll
        for (int c = 0; c < 8; ++c)
            acc[c] += p * bf2f((ushort_t)u[c]);
    }
    den += __shfl_xor(den, 32);
    #pragma unroll
    for (int c = 0; c < 8; ++c) acc[c] += __shfl_xor(acc[c], 32);

    const float inv = 1.f / (den + 1e-16f);
    short8v hr = *(const short8v*)(hresb + (size_t)n * HID + ch0);
    float4 gbA = *(const float4*)(gb + ch0);
    float4 gbB = *(const float4*)(gb + ch0 + 4);
    float v[8];
    #pragma unroll
    for (int c = 0; c < 8; ++c) {
        float gbv = (c < 4) ? ((const float*)&gbA)[c] : ((const float*)&gbB)[c - 4];
        v[c] = acc[c] * inv + bf2f((ushort_t)hr[c]) + gbv;
    }
    float s = 0.f;
    #pragma unroll
    for (int c = 0; c < 8; ++c) s += v[c];
    #pragma unroll
    for (int d = 1; d < 32; d <<= 1) s += __shfl_xor(s, d);
    const float mu = s * (1.f / HID);
    float q = 0.f;
    #pragma unroll
    for (int c = 0; c < 8; ++c) {
        v[c] -= mu;
        q += v[c] * v[c];
    }
    #pragma unroll
    for (int d = 1; d < 32; d <<= 1) q += __shfl_xor(q, d);
    const float rstd = rsqrtf(q * (1.f / HID) + LN_EPS);
    float4 gA = *(const float4*)(g + ch0);
    float4 gB = *(const float4*)(g + ch0 + 4);
    float4 bA = *(const float4*)(b + ch0);
    float4 bB = *(const float4*)(b + ch0 + 4);
    ushort_t o[8];
    #pragma unroll
    for (int c = 0; c < 8; ++c) {
        float gv = (c < 4) ? ((const float*)&gA)[c] : ((const float*)&gB)[c - 4];
        float bv = (c < 4) ? ((const float*)&bA)[c] : ((const float*)&bB)[c - 4];
        o[c] = f2bf(fmaxf(v[c] * rstd * gv + bv, 0.f));
    }
    if (half == 0)
        *(short8v*)(hb + (size_t)n * HID + ch0) = *(short8v*)o;
}

// ---------------------------------------------------------------- pooling
__global__ __launch_bounds__(256) void k_pool1(const ushort_t* __restrict__ hb,
                                               const int* __restrict__ rowstart,
                                               float* __restrict__ part) {
    int g = blockIdx.x, p = blockIdx.y, c = threadIdx.x;
    int s0 = rowstart[g], s1 = rowstart[g + 1];
    float sum = 0.f, mx = -INFINITY;
    for (int n = s0 + p; n < s1; n += POOL_P) {
        float v = bf2f(hb[(size_t)n * HID + c]);
        sum += v;
        mx = fmaxf(mx, v);
    }
    float* pp = part + (size_t)(g * POOL_P + p) * 512;
    pp[c] = sum;
    pp[256 + c] = mx;
}

__global__ __launch_bounds__(256) void k_pool2g(const float* __restrict__ part,
                                                const int* __restrict__ rowstart,
                                                const float* __restrict__ W,
                                                const float* __restrict__ bias,
                                                float* __restrict__ out) {
    __shared__ float hc[512];
    int g = blockIdx.x, c = threadIdx.x;
    float sum = 0.f, mx = -INFINITY;
    for (int p = 0; p < POOL_P; ++p) {
        const float* pp = part + (size_t)(g * POOL_P + p) * 512;
        sum += pp[c];
        mx = fmaxf(mx, pp[256 + c]);
    }
    float cntf = (float)(rowstart[g + 1] - rowstart[g]);
    hc[c] = sum / fmaxf(cntf, 1.f);
    hc[256 + c] = mx;
    __syncthreads();
    float acc = bias[c];
    #pragma unroll 8
    for (int k = 0; k < 2 * HID; ++k)
        acc += hc[k] * W[(size_t)k * HID + c];
    out[(size_t)g * HID + c] = fmaxf(acc, 0.f);
}

// ---------------------------------------------------------------- launch
extern "C" void kernel_launch(void* const* d_in, const int* in_sizes, int n_in,
                              void* d_out, int out_size, void* d_ws, size_t ws_size,
                              hipStream_t stream) {
    const float* x       = (const float*)d_in[0];
    const int*   ei      = (const int*)d_in[1];
    const int*   batch   = (const int*)d_in[2];
    const float* in_w    = (const float*)d_in[3];
    const float* in_b    = (const float*)d_in[4];
    const float* gat_w   = (const float*)d_in[5];
    const float* att_src = (const float*)d_in[6];
    const float* att_dst = (const float*)d_in[7];
    const float* gat_b   = (const float*)d_in[8];
    const float* res_w   = (const float*)d_in[9];
    const float* res_b   = (const float*)d_in[10];
    const float* ln_g    = (const float*)d_in[11];
    const float* ln_b    = (const float*)d_in[12];
    const float* pool_w  = (const float*)d_in[13];
    const float* pool_b  = (const float*)d_in[14];
    float* out = (float*)d_out;

    char* ws = (char*)d_ws;
    size_t off = 0;
    auto alloc = [&](size_t bytes) -> char* {
        char* p = ws + off;
        off = (off + bytes + 255) & ~(size_t)255;
        return p;
    };
    ushort_t* xb    = (ushort_t*)alloc((size_t)M_PAD * FDIM * 2);
    ushort_t* hb    = (ushort_t*)alloc((size_t)M_PAD * HID * 2);
    ushort_t* xhb   = (ushort_t*)alloc((size_t)M_PAD * HID * 2);
    ushort_t* hresb = (ushort_t*)alloc((size_t)M_PAD * HID * 2);
    float* asn      = (float*)alloc((size_t)N_NODES * HEADS * 4);
    float* adn      = (float*)alloc((size_t)N_NODES * HEADS * 4);
    int*   cnt      = (int*)alloc((size_t)N_NODES * 4);
    int*   fill     = (int*)alloc((size_t)N_NODES * 4);
    int*   rowptr   = (int*)alloc((size_t)(N_NODES + 1) * 4);
    int*   colv     = (int*)alloc((size_t)E2 * 4);
    int*   part     = (int*)alloc(256 * 4);
    int*   rowstart = (int*)alloc((size_t)(GRAPHS + 1) * 4);
    ushort_t* wt2   = (ushort_t*)alloc((size_t)LAYERS * 512 * HID * 2);
    ushort_t* wtC   = (ushort_t*)alloc((size_t)512 * FDIM * 2);
    float* bC0      = (float*)alloc(HID * 4);
    float* bC1      = (float*)alloc(HID * 4);
    float* poolpart = (float*)alloc((size_t)GRAPHS * POOL_P * 512 * 4);

    hipMemsetAsync(cnt, 0, (size_t)N_NODES * 4, stream);
    hipMemsetAsync(fill, 0, (size_t)N_NODES * 4, stream);

    const int nb = (N_NODES + 255) / 256;

    // fused prep: wcomb (first, LPT) + cast_x + count + bounds + wtrans
    k_prep2<<<PREP2_BLOCKS, 256, 0, stream>>>(x, ei, batch, in_w, in_b,
                                              gat_w, res_w, res_b,
                                              xb, cnt, rowstart, wt2,
                                              wtC, bC0, bC1);
    k_scan1<<<nb, 256, 0, stream>>>(cnt, part);
    k_scan2<<<1, 256, 0, stream>>>(part, nb, rowptr);
    k_scan3<<<nb, 256, 0, stream>>>(cnt, part, rowptr);

    const int nw = (N_NODES + 3) / 4;

    // ---- layer 0 GEMM (K=512) + CSR fill fused ----
    k_gemm_bf16<FDIM><<<GEMM_BLOCKS + FILL_BLK, 512, 0, stream>>>(
        xb, wtC, bC0, bC1, hresb, xhb, att_src, att_dst, asn, adn, N_NODES,
        ei, rowptr, fill, colv);
    k_agg_ln<<<nw, 256, 0, stream>>>(xhb, asn, adn, rowptr, colv, hresb,
                                     gat_b, ln_g, ln_b, hb);

    // ---- layers 1..2: A = hb, K = 256 (no fill segment) ----
    for (int i = 1; i < LAYERS; ++i) {
        k_gemm_bf16<HID><<<GEMM_BLOCKS, 512, 0, stream>>>(
            hb, wt2 + (size_t)i * 512 * HID,
            res_b + (size_t)i * HID, nullptr, hresb, xhb,
            att_src + (size_t)i * HEADS * CDIM,
            att_dst + (size_t)i * HEADS * CDIM, asn, adn, N_NODES,
            nullptr, nullptr, nullptr, nullptr);
        k_agg_ln<<<nw, 256, 0, stream>>>(xhb, asn, adn, rowptr, colv, hresb,
                                         gat_b + (size_t)i * HID,
                                         ln_g + (size_t)i * HID,
                                         ln_b + (size_t)i * HID, hb);
    }
    dim3 pg(GRAPHS, POOL_P);
    k_pool1<<<pg, 256, 0, stream>>>(hb, rowstart, poolpart);
    k_pool2g<<<GRAPHS, 256, 0, stream>>>(poolpart, rowstart, pool_w, pool_b, out);
}